// Round 2
// baseline (637.073 us; speedup 1.0000x reference)
//
#include <hip/hip_runtime.h>
#include <cstdint>

#define B_ 32
#define N_ 64
#define H_ 128
#define S_ 100
#define C_ 16
#define SIGMA_ 0.5f

// output layout (floats): x_new | adj_new | assignments | x_emb | mask_new
#define OFF_XNEW 0
#define OFF_ADJN 262144
#define OFF_ASGN 393216
#define OFF_XEMB 598016
#define OFF_MSKN 860160

// ---- mask dtype sniffing: mask[0,0] is guaranteed true (counts >= 32) ----
__device__ __forceinline__ int read_mask_elem(const void* mp, int idx) {
    const unsigned int* u = (const unsigned int*)mp;
    const unsigned int w0 = u[0], w1 = u[1];
    if (w0 == 1u) {
        if (w1 == 1u) return ((const int*)mp)[idx] != 0;      // int32 (elem1 also true)
        return ((const int*)mp)[2 * idx] != 0;                 // int64
    }
    if (w0 == 0x3f800000u) return ((const float*)mp)[idx] != 0.0f;   // float32
    if (w0 == 0u) return ((const double*)mp)[idx] != 0.0;            // float64
    return ((const unsigned char*)mp)[idx] != 0;                     // bool bytes
}

// ================= Kernel A: 2-layer GCN, adj/mask bitmasks =================
__global__ __launch_bounds__(256) void gcn_kernel(
    const float* __restrict__ x, const float* __restrict__ adj,
    const void* __restrict__ maskp,
    const float* __restrict__ W1, const float* __restrict__ b1,
    const float* __restrict__ W2, const float* __restrict__ b2,
    float* __restrict__ out,
    unsigned long long* __restrict__ abits_ws,
    unsigned long long* __restrict__ mbits_ws)
{
    const int b = blockIdx.x;
    const int t = threadIdx.x;
    __shared__ float Xs[N_][130];   // padded strides to cut bank conflicts
    __shared__ float Hs[N_][130];
    __shared__ float An[N_][65];
    __shared__ float dsh[N_];
    __shared__ unsigned long long mb_sh;

    if (t < 64) {
        const int mv = read_mask_elem(maskp, b * N_ + t);
        const unsigned long long bal = __ballot(mv != 0);
        if (t == 0) { mb_sh = bal; mbits_ws[b] = bal; }
    }
    // adj -> An (diag forced to 1 for normalization) + adjacency bitmasks (ORIGINAL adj)
    for (int row = (t >> 6); row < N_; row += 4) {
        const int j = t & 63;
        const float v = adj[((size_t)b * N_ + row) * N_ + j];
        const unsigned long long bal = __ballot(v > 0.0f);
        if (j == 0) abits_ws[b * N_ + row] = bal;
        An[row][j] = (row == j) ? 1.0f : v;
    }
    __syncthreads();
    if (t < 64) {
        float s = 0.0f;
        for (int j = 0; j < N_; ++j) s += An[t][j];
        if (s < 1.0f) s = 1.0f;
        dsh[t] = 1.0f / sqrtf(s);
    }
    __syncthreads();
    for (int e = t; e < N_ * N_; e += 256) {
        const int i = e >> 6, j = e & 63;
        An[i][j] *= dsh[i] * dsh[j];
    }
    for (int e = t; e < N_ * H_; e += 256)
        Xs[e >> 7][e & 127] = x[(size_t)b * N_ * H_ + e];
    __syncthreads();

    const int ng = t & 15, kg = t >> 4;          // 4 nodes x 8 contiguous k per thread
    const unsigned long long mb = mb_sh;

    // ---- layer 1: Hs = Xs @ W1 ----
    {
        float acc[4][8] = {};
        for (int d = 0; d < H_; ++d) {
            float xv[4];
#pragma unroll
            for (int r = 0; r < 4; ++r) xv[r] = Xs[4 * ng + r][d];
            const float4 wa = *(const float4*)(W1 + d * H_ + 8 * kg);
            const float4 wb = *(const float4*)(W1 + d * H_ + 8 * kg + 4);
            const float wf[8] = {wa.x, wa.y, wa.z, wa.w, wb.x, wb.y, wb.z, wb.w};
#pragma unroll
            for (int j = 0; j < 8; ++j)
#pragma unroll
                for (int r = 0; r < 4; ++r) acc[r][j] += xv[r] * wf[j];
        }
#pragma unroll
        for (int r = 0; r < 4; ++r)
#pragma unroll
            for (int j = 0; j < 8; ++j) Hs[4 * ng + r][8 * kg + j] = acc[r][j];
    }
    __syncthreads();
    // ---- xe = relu(An @ Hs + b1) * mask -> Xs ----
    {
        float acc[4][8] = {};
        for (int j2 = 0; j2 < N_; ++j2) {
            float av[4];
#pragma unroll
            for (int r = 0; r < 4; ++r) av[r] = An[4 * ng + r][j2];
            float hv[8];
#pragma unroll
            for (int j = 0; j < 8; ++j) hv[j] = Hs[j2][8 * kg + j];
#pragma unroll
            for (int j = 0; j < 8; ++j)
#pragma unroll
                for (int r = 0; r < 4; ++r) acc[r][j] += av[r] * hv[j];
        }
        const float4 ba = *(const float4*)(b1 + 8 * kg);
        const float4 bb = *(const float4*)(b1 + 8 * kg + 4);
        const float bf[8] = {ba.x, ba.y, ba.z, ba.w, bb.x, bb.y, bb.z, bb.w};
#pragma unroll
        for (int r = 0; r < 4; ++r) {
            const int i = 4 * ng + r;
            const float m = ((mb >> i) & 1ull) ? 1.0f : 0.0f;
#pragma unroll
            for (int j = 0; j < 8; ++j)
                Xs[i][8 * kg + j] = fmaxf(acc[r][j] + bf[j], 0.0f) * m;
        }
    }
    __syncthreads();
    // ---- layer 2: Hs = Xs @ W2 ----
    {
        float acc[4][8] = {};
        for (int d = 0; d < H_; ++d) {
            float xv[4];
#pragma unroll
            for (int r = 0; r < 4; ++r) xv[r] = Xs[4 * ng + r][d];
            const float4 wa = *(const float4*)(W2 + d * H_ + 8 * kg);
            const float4 wb = *(const float4*)(W2 + d * H_ + 8 * kg + 4);
            const float wf[8] = {wa.x, wa.y, wa.z, wa.w, wb.x, wb.y, wb.z, wb.w};
#pragma unroll
            for (int j = 0; j < 8; ++j)
#pragma unroll
                for (int r = 0; r < 4; ++r) acc[r][j] += xv[r] * wf[j];
        }
        __syncthreads();
#pragma unroll
        for (int r = 0; r < 4; ++r)
#pragma unroll
            for (int j = 0; j < 8; ++j) Hs[4 * ng + r][8 * kg + j] = acc[r][j];
    }
    __syncthreads();
    // ---- x_emb = relu(An @ Hs + b2) * mask -> global ----
    {
        float acc[4][8] = {};
        for (int j2 = 0; j2 < N_; ++j2) {
            float av[4];
#pragma unroll
            for (int r = 0; r < 4; ++r) av[r] = An[4 * ng + r][j2];
            float hv[8];
#pragma unroll
            for (int j = 0; j < 8; ++j) hv[j] = Hs[j2][8 * kg + j];
#pragma unroll
            for (int j = 0; j < 8; ++j)
#pragma unroll
                for (int r = 0; r < 4; ++r) acc[r][j] += av[r] * hv[j];
        }
        const float4 ba = *(const float4*)(b2 + 8 * kg);
        const float4 bb = *(const float4*)(b2 + 8 * kg + 4);
        const float bf[8] = {ba.x, ba.y, ba.z, ba.w, bb.x, bb.y, bb.z, bb.w};
#pragma unroll
        for (int r = 0; r < 4; ++r) {
            const int i = 4 * ng + r;
            const float m = ((mb >> i) & 1ull) ? 1.0f : 0.0f;
#pragma unroll
            for (int j = 0; j < 8; ++j)
                out[OFF_XEMB + (size_t)b * N_ * H_ + i * H_ + 8 * kg + j] =
                    fmaxf(acc[r][j] + bf[j], 0.0f) * m;
        }
    }
}

// ---- helpers: reduce-scatter 16 values over 16 contiguous lanes ----
__device__ __forceinline__ float rscat16(float* v, int kg) {
#pragma unroll
    for (int i = 0; i < 8; ++i) {
        const float send = (kg & 8) ? v[i] : v[i + 8];
        const float recv = __shfl_xor(send, 8);
        v[i] = ((kg & 8) ? v[i + 8] : v[i]) + recv;
    }
#pragma unroll
    for (int i = 0; i < 4; ++i) {
        const float send = (kg & 4) ? v[i] : v[i + 4];
        const float recv = __shfl_xor(send, 4);
        v[i] = ((kg & 4) ? v[i + 4] : v[i]) + recv;
    }
#pragma unroll
    for (int i = 0; i < 2; ++i) {
        const float send = (kg & 2) ? v[i] : v[i + 2];
        const float recv = __shfl_xor(send, 2);
        v[i] = ((kg & 2) ? v[i + 2] : v[i]) + recv;
    }
    {
        const float send = (kg & 1) ? v[0] : v[1];
        const float recv = __shfl_xor(send, 1);
        v[0] = ((kg & 1) ? v[1] : v[0]) + recv;
    }
    return v[0];   // lane kg holds full sum for index kg
}

// argmax over the 16-lane group (value bv at concept kg); first-max tie-break
__device__ __forceinline__ void argmax16(float bv, int kg, int* dst) {
    int bi = kg;
#pragma unroll
    for (int m = 1; m <= 8; m <<= 1) {
        const float ov = __shfl_xor(bv, m);
        const int   oi = __shfl_xor(bi, m);
        if (ov > bv || (ov == bv && oi < bi)) { bv = ov; bi = oi; }
    }
    if (kg == 0) *dst = bi;
}

// ========= Kernel B: per (sample,batch) — MLP, argmax, components, pooling =========
__global__ __launch_bounds__(256, 4) void sample_kernel(
    const float* __restrict__ noise,
    const float* __restrict__ cW1, const float* __restrict__ cb1,
    const float* __restrict__ cW2, const float* __restrict__ cb2,
    const unsigned long long* __restrict__ abits_ws,
    const unsigned long long* __restrict__ mbits_ws,
    float* __restrict__ out, int* __restrict__ gNcl)
{
    const int sb = blockIdx.x;
    const int b  = sb & (B_ - 1);
    const int t  = threadIdx.x;
    __shared__ float xa[N_ * H_];    // x_all, chunk-XOR-swizzled: chunk cc of row i at cc^(i&7)
    __shared__ int   concepts[N_];
    __shared__ unsigned long long reachL[N_];
    __shared__ unsigned long long cmS[N_];
    __shared__ unsigned long long roS[N_];
    __shared__ unsigned long long abS[N_];
    __shared__ unsigned int presLo, presHi;

    const unsigned long long mb = mbits_ws[b];
    if (t < 64) abS[t] = abits_ws[b * N_ + t];
    if (t == 0) { presLo = 0u; presHi = 0u; }

    // stage xa = x_emb[b] + 0.5*noise[sb]
    {
        const float4* e4 = (const float4*)(out + OFF_XEMB + (size_t)b * N_ * H_);
        const float4* n4 = (const float4*)(noise + (size_t)sb * N_ * H_);
        float4* x4 = (float4*)xa;
        for (int idx = t; idx < N_ * 32; idx += 256) {
            const int i = idx >> 5, cc = idx & 31;
            const float4 ev = e4[idx], nv = n4[idx];
            float4 v;
            v.x = ev.x + SIGMA_ * nv.x;  v.y = ev.y + SIGMA_ * nv.y;
            v.z = ev.z + SIGMA_ * nv.z;  v.w = ev.w + SIGMA_ * nv.w;
            x4[i * 32 + (cc ^ (i & 7))] = v;
        }
    }
    __syncthreads();

    // ---- fused: hidden = relu(xa@cW1+cb1); logits = hidden@cW2+cb2; argmax ----
    // thread t: node group ng = t>>4 (nodes 4ng..4ng+3), k chunk kg = t&15 (k in [8kg,8kg+8))
    const int ng = t >> 4, kg = t & 15;
    float acc[4][8] = {};
    {
        const float4* x4 = (const float4*)xa;
        const int swzb = 4 * (ng & 1);
        for (int cc = 0; cc < 32; ++cc) {
            float xv[4][4];
#pragma unroll
            for (int r = 0; r < 4; ++r) {
                const float4 tmp = x4[(4 * ng + r) * 32 + (cc ^ (swzb + r))];
                xv[r][0] = tmp.x; xv[r][1] = tmp.y; xv[r][2] = tmp.z; xv[r][3] = tmp.w;
            }
#pragma unroll
            for (int dd = 0; dd < 4; ++dd) {
                const int d = cc * 4 + dd;
                const float4 wa = *(const float4*)(cW1 + d * H_ + 8 * kg);
                const float4 wb = *(const float4*)(cW1 + d * H_ + 8 * kg + 4);
                const float wf[8] = {wa.x, wa.y, wa.z, wa.w, wb.x, wb.y, wb.z, wb.w};
#pragma unroll
                for (int j = 0; j < 8; ++j)
#pragma unroll
                    for (int r = 0; r < 4; ++r) acc[r][j] += xv[r][dd] * wf[j];
            }
        }
    }
    {
        const float4 ba = *(const float4*)(cb1 + 8 * kg);
        const float4 bb = *(const float4*)(cb1 + 8 * kg + 4);
        const float bf[8] = {ba.x, ba.y, ba.z, ba.w, bb.x, bb.y, bb.z, bb.w};
        const float cb2v = cb2[kg];
        // process nodes in pairs to bound registers; cW2 rows re-read from L1
#pragma unroll 1
        for (int pp = 0; pp < 2; ++pp) {
            float h0[8], h1[8];
#pragma unroll
            for (int j = 0; j < 8; ++j) {
                h0[j] = fmaxf(acc[2 * pp][j] + bf[j], 0.0f);
                h1[j] = fmaxf(acc[2 * pp + 1][j] + bf[j], 0.0f);
            }
            float pl0[16] = {}, pl1[16] = {};
#pragma unroll
            for (int j = 0; j < 8; ++j) {
                const float4* w2r = (const float4*)(cW2 + (8 * kg + j) * C_);
                const float4 w0 = w2r[0], w1 = w2r[1], w2v = w2r[2], w3 = w2r[3];
                const float wf2[16] = {w0.x, w0.y, w0.z, w0.w, w1.x, w1.y, w1.z, w1.w,
                                       w2v.x, w2v.y, w2v.z, w2v.w, w3.x, w3.y, w3.z, w3.w};
#pragma unroll
                for (int c = 0; c < C_; ++c) {
                    pl0[c] += h0[j] * wf2[c];
                    pl1[c] += h1[j] * wf2[c];
                }
            }
            const float l0 = rscat16(pl0, kg) + cb2v;   // lane kg: logit[node][concept kg]
            const float l1 = rscat16(pl1, kg) + cb2v;
            argmax16(l0, kg, &concepts[4 * ng + 2 * pp]);
            argmax16(l1, kg, &concepts[4 * ng + 2 * pp + 1]);
        }
    }
    __syncthreads();

    // ---- connected components on same-concept masked subgraph via bitset closure ----
    unsigned long long reach = 0ull;
    int masked_i = 0;
    if (t < 64) {
        masked_i = (int)((mb >> t) & 1ull);
        if (masked_i) {
            const int ci = concepts[t];
            unsigned long long mm = abS[t] & mb;
            unsigned long long em = 0ull;
            while (mm) {
                const int j = __builtin_ctzll(mm);
                if (concepts[j] == ci) em |= (1ull << j);
                mm &= mm - 1;
            }
            reach = em | (1ull << t);
        }
        reachL[t] = reach;
    }
    __syncthreads();
    for (;;) {                                    // fixpoint with early exit
        unsigned long long r = reach;
        if (masked_i) {
            unsigned long long mm = reach & ~(1ull << t);
            while (mm) {
                const int j = __builtin_ctzll(mm);
                r |= reachL[j];
                mm &= mm - 1;
            }
        }
        const int changed = (r != reach);
        __syncthreads();
        if (t < 64) reachL[t] = r;
        reach = r;
        if (!__syncthreads_or(changed)) break;
    }
    int root = 0;
    if (masked_i) {
        root = __builtin_ctzll(reach);           // min node index in component
        if (root < 32) atomicOr(&presLo, 1u << root);
        else           atomicOr(&presHi, 1u << (root - 32));
    }
    __syncthreads();
    const unsigned long long present =
        ((unsigned long long)presHi << 32) | (unsigned long long)presLo;
    const int ncl = __popcll(present);
    if (t < 64) {
        int a_i = 0;
        if (masked_i) {
            a_i = __popcll(present & ((1ull << root) - 1ull)) + 1;   // compact 1-based id
            if (root == t) {                     // component representative
                cmS[a_i - 1] = reach;            // member bitmask
                unsigned long long ro = 0ull, mm = reach;
                while (mm) { const int j = __builtin_ctzll(mm); ro |= abS[j]; mm &= mm - 1; }
                roS[a_i - 1] = ro;               // OR of adjacency rows of members
            }
        }
        out[OFF_ASGN + (size_t)sb * N_ + t] = (float)a_i;
    }
    __syncthreads();

    // ---- x_new: gather per (cluster, d) over member bitmask, one global atomic each ----
    for (int e = t; e < ncl * H_; e += 256) {
        const int c = e >> 7, d = e & 127;
        unsigned long long mm = cmS[c];
        float s = 0.0f;
        while (mm) {
            const int j = __builtin_ctzll(mm);
            s += xa[j * H_ + ((((d >> 2) ^ (j & 7)) << 2) | (d & 3))];
            mm &= mm - 1;
        }
        atomicAdd(&out[OFF_XNEW + (size_t)b * N_ * H_ + e], s);
    }
    // ---- adj_new: count (0/1) connections between clusters ----
    {
        int* adjCnt = (int*)out + OFF_ADJN;
        for (int idx = t; idx < ncl * N_; idx += 256) {
            const int c1 = idx >> 6, c2 = idx & 63;
            if (c2 < ncl && (roS[c1] & cmS[c2]))
                atomicAdd(&adjCnt[b * N_ * N_ + idx], 1);
        }
    }
    if (t == 0) atomicMax(&gNcl[b], ncl);
}

// ================= Kernel C: finalize (means, mask_new) =================
__global__ __launch_bounds__(256) void finalize_kernel(
    float* __restrict__ out, const int* __restrict__ gNcl)
{
    const int idx = blockIdx.x * 256 + threadIdx.x;
    if (idx < OFF_ADJN) {
        out[idx] = out[idx] / 100.0f;                     // x_new mean over S=100
    } else if (idx < OFF_ASGN) {
        const int c = ((const int*)out)[idx];             // adj counts accumulated as int
        out[idx] = (float)c / 100.0f;
    } else {
        const int m = idx - OFF_ASGN;
        if (m < B_ * N_) {
            const int bb = m >> 6, k = m & 63;
            out[OFF_MSKN + m] = (k < gNcl[bb]) ? 1.0f : 0.0f;
        }
    }
}

extern "C" void kernel_launch(void* const* d_in, const int* in_sizes, int n_in,
                              void* d_out, int out_size, void* d_ws, size_t ws_size,
                              hipStream_t stream) {
    (void)in_sizes; (void)n_in; (void)out_size; (void)ws_size;
    const float* x    = (const float*)d_in[0];
    const float* adj  = (const float*)d_in[1];
    const void*  mskp = d_in[2];
    const float* W1   = (const float*)d_in[3];
    const float* b1   = (const float*)d_in[4];
    const float* W2   = (const float*)d_in[5];
    const float* b2   = (const float*)d_in[6];
    const float* cW1  = (const float*)d_in[7];
    const float* cb1  = (const float*)d_in[8];
    const float* cW2  = (const float*)d_in[9];
    const float* cb2  = (const float*)d_in[10];
    const float* noise = (const float*)d_in[11];
    float* out = (float*)d_out;

    // ws: [0,256) gNcl (32 ints), [256, 256+16384) adjacency bitmasks, then mask bitmasks
    int* gNcl = (int*)d_ws;
    unsigned long long* abits_ws = (unsigned long long*)((char*)d_ws + 256);
    unsigned long long* mbits_ws = (unsigned long long*)((char*)d_ws + 256 + 16384);

    hipMemsetAsync(d_out, 0, (size_t)OFF_ASGN * sizeof(float), stream); // zero x_new + adj_new accumulators
    hipMemsetAsync(d_ws, 0, 256, stream);                               // zero gNcl

    gcn_kernel<<<B_, 256, 0, stream>>>(x, adj, mskp, W1, b1, W2, b2,
                                       out, abits_ws, mbits_ws);
    sample_kernel<<<S_ * B_, 256, 0, stream>>>(noise, cW1, cb1, cW2, cb2,
                                               abits_ws, mbits_ws, out, gNcl);
    finalize_kernel<<<(OFF_ASGN + B_ * N_ + 255) / 256, 256, 0, stream>>>(out, gNcl);
}

// Round 3
// 528.329 us; speedup vs baseline: 1.2058x; 1.2058x over previous
//
#include <hip/hip_runtime.h>
#include <cstdint>

#define B_ 32
#define N_ 64
#define H_ 128
#define S_ 100
#define C_ 16
#define SIGMA_ 0.5f

// output layout (floats): x_new | adj_new | assignments | x_emb | mask_new
#define OFF_XNEW 0
#define OFF_ADJN 262144
#define OFF_ASGN 393216
#define OFF_XEMB 598016
#define OFF_MSKN 860160

// ---- mask dtype sniffing: mask[0,0] is guaranteed true (counts >= 32) ----
__device__ __forceinline__ int read_mask_elem(const void* mp, int idx) {
    const unsigned int* u = (const unsigned int*)mp;
    const unsigned int w0 = u[0], w1 = u[1];
    if (w0 == 1u) {
        if (w1 == 1u) return ((const int*)mp)[idx] != 0;      // int32 (elem1 also true)
        return ((const int*)mp)[2 * idx] != 0;                 // int64
    }
    if (w0 == 0x3f800000u) return ((const float*)mp)[idx] != 0.0f;   // float32
    if (w0 == 0u) return ((const double*)mp)[idx] != 0.0;            // float64
    return ((const unsigned char*)mp)[idx] != 0;                     // bool bytes
}

// ================= Kernel A: 2-layer GCN, adj/mask bitmasks =================
__global__ __launch_bounds__(256) void gcn_kernel(
    const float* __restrict__ x, const float* __restrict__ adj,
    const void* __restrict__ maskp,
    const float* __restrict__ W1, const float* __restrict__ b1,
    const float* __restrict__ W2, const float* __restrict__ b2,
    float* __restrict__ out,
    unsigned long long* __restrict__ abits_ws,
    unsigned long long* __restrict__ mbits_ws)
{
    const int b = blockIdx.x;
    const int t = threadIdx.x;
    __shared__ float Xs[N_][130];   // padded strides to cut bank conflicts
    __shared__ float Hs[N_][130];
    __shared__ float An[N_][65];
    __shared__ float dsh[N_];
    __shared__ unsigned long long mb_sh;

    if (t < 64) {
        const int mv = read_mask_elem(maskp, b * N_ + t);
        const unsigned long long bal = __ballot(mv != 0);
        if (t == 0) { mb_sh = bal; mbits_ws[b] = bal; }
    }
    // adj -> An (diag forced to 1 for normalization) + adjacency bitmasks (ORIGINAL adj)
    for (int row = (t >> 6); row < N_; row += 4) {
        const int j = t & 63;
        const float v = adj[((size_t)b * N_ + row) * N_ + j];
        const unsigned long long bal = __ballot(v > 0.0f);
        if (j == 0) abits_ws[b * N_ + row] = bal;
        An[row][j] = (row == j) ? 1.0f : v;
    }
    __syncthreads();
    if (t < 64) {
        float s = 0.0f;
        for (int j = 0; j < N_; ++j) s += An[t][j];
        if (s < 1.0f) s = 1.0f;
        dsh[t] = 1.0f / sqrtf(s);
    }
    __syncthreads();
    for (int e = t; e < N_ * N_; e += 256) {
        const int i = e >> 6, j = e & 63;
        An[i][j] *= dsh[i] * dsh[j];
    }
    for (int e = t; e < N_ * H_; e += 256)
        Xs[e >> 7][e & 127] = x[(size_t)b * N_ * H_ + e];
    __syncthreads();

    const int ng = t & 15, kg = t >> 4;          // 4 nodes x 8 contiguous k per thread
    const unsigned long long mb = mb_sh;

    // ---- layer 1: Hs = Xs @ W1 ----
    {
        float acc[4][8] = {};
        for (int d = 0; d < H_; ++d) {
            float xv[4];
#pragma unroll
            for (int r = 0; r < 4; ++r) xv[r] = Xs[4 * ng + r][d];
            const float4 wa = *(const float4*)(W1 + d * H_ + 8 * kg);
            const float4 wb = *(const float4*)(W1 + d * H_ + 8 * kg + 4);
            const float wf[8] = {wa.x, wa.y, wa.z, wa.w, wb.x, wb.y, wb.z, wb.w};
#pragma unroll
            for (int j = 0; j < 8; ++j)
#pragma unroll
                for (int r = 0; r < 4; ++r) acc[r][j] += xv[r] * wf[j];
        }
#pragma unroll
        for (int r = 0; r < 4; ++r)
#pragma unroll
            for (int j = 0; j < 8; ++j) Hs[4 * ng + r][8 * kg + j] = acc[r][j];
    }
    __syncthreads();
    // ---- xe = relu(An @ Hs + b1) * mask -> Xs ----
    {
        float acc[4][8] = {};
        for (int j2 = 0; j2 < N_; ++j2) {
            float av[4];
#pragma unroll
            for (int r = 0; r < 4; ++r) av[r] = An[4 * ng + r][j2];
            float hv[8];
#pragma unroll
            for (int j = 0; j < 8; ++j) hv[j] = Hs[j2][8 * kg + j];
#pragma unroll
            for (int j = 0; j < 8; ++j)
#pragma unroll
                for (int r = 0; r < 4; ++r) acc[r][j] += av[r] * hv[j];
        }
        const float4 ba = *(const float4*)(b1 + 8 * kg);
        const float4 bb = *(const float4*)(b1 + 8 * kg + 4);
        const float bf[8] = {ba.x, ba.y, ba.z, ba.w, bb.x, bb.y, bb.z, bb.w};
#pragma unroll
        for (int r = 0; r < 4; ++r) {
            const int i = 4 * ng + r;
            const float m = ((mb >> i) & 1ull) ? 1.0f : 0.0f;
#pragma unroll
            for (int j = 0; j < 8; ++j)
                Xs[i][8 * kg + j] = fmaxf(acc[r][j] + bf[j], 0.0f) * m;
        }
    }
    __syncthreads();
    // ---- layer 2: Hs = Xs @ W2 ----
    {
        float acc[4][8] = {};
        for (int d = 0; d < H_; ++d) {
            float xv[4];
#pragma unroll
            for (int r = 0; r < 4; ++r) xv[r] = Xs[4 * ng + r][d];
            const float4 wa = *(const float4*)(W2 + d * H_ + 8 * kg);
            const float4 wb = *(const float4*)(W2 + d * H_ + 8 * kg + 4);
            const float wf[8] = {wa.x, wa.y, wa.z, wa.w, wb.x, wb.y, wb.z, wb.w};
#pragma unroll
            for (int j = 0; j < 8; ++j)
#pragma unroll
                for (int r = 0; r < 4; ++r) acc[r][j] += xv[r] * wf[j];
        }
        __syncthreads();
#pragma unroll
        for (int r = 0; r < 4; ++r)
#pragma unroll
            for (int j = 0; j < 8; ++j) Hs[4 * ng + r][8 * kg + j] = acc[r][j];
    }
    __syncthreads();
    // ---- x_emb = relu(An @ Hs + b2) * mask -> global ----
    {
        float acc[4][8] = {};
        for (int j2 = 0; j2 < N_; ++j2) {
            float av[4];
#pragma unroll
            for (int r = 0; r < 4; ++r) av[r] = An[4 * ng + r][j2];
            float hv[8];
#pragma unroll
            for (int j = 0; j < 8; ++j) hv[j] = Hs[j2][8 * kg + j];
#pragma unroll
            for (int j = 0; j < 8; ++j)
#pragma unroll
                for (int r = 0; r < 4; ++r) acc[r][j] += av[r] * hv[j];
        }
        const float4 ba = *(const float4*)(b2 + 8 * kg);
        const float4 bb = *(const float4*)(b2 + 8 * kg + 4);
        const float bf[8] = {ba.x, ba.y, ba.z, ba.w, bb.x, bb.y, bb.z, bb.w};
#pragma unroll
        for (int r = 0; r < 4; ++r) {
            const int i = 4 * ng + r;
            const float m = ((mb >> i) & 1ull) ? 1.0f : 0.0f;
#pragma unroll
            for (int j = 0; j < 8; ++j)
                out[OFF_XEMB + (size_t)b * N_ * H_ + i * H_ + 8 * kg + j] =
                    fmaxf(acc[r][j] + bf[j], 0.0f) * m;
        }
    }
}

// ---- helpers: reduce-scatter 16 values over 16 contiguous lanes ----
__device__ __forceinline__ float rscat16(float* v, int kg) {
#pragma unroll
    for (int i = 0; i < 8; ++i) {
        const float send = (kg & 8) ? v[i] : v[i + 8];
        const float recv = __shfl_xor(send, 8);
        v[i] = ((kg & 8) ? v[i + 8] : v[i]) + recv;
    }
#pragma unroll
    for (int i = 0; i < 4; ++i) {
        const float send = (kg & 4) ? v[i] : v[i + 4];
        const float recv = __shfl_xor(send, 4);
        v[i] = ((kg & 4) ? v[i + 4] : v[i]) + recv;
    }
#pragma unroll
    for (int i = 0; i < 2; ++i) {
        const float send = (kg & 2) ? v[i] : v[i + 2];
        const float recv = __shfl_xor(send, 2);
        v[i] = ((kg & 2) ? v[i + 2] : v[i]) + recv;
    }
    {
        const float send = (kg & 1) ? v[0] : v[1];
        const float recv = __shfl_xor(send, 1);
        v[0] = ((kg & 1) ? v[1] : v[0]) + recv;
    }
    return v[0];   // lane kg holds full sum for index kg
}

// argmax over the 16-lane group (value bv at concept kg); first-max tie-break
__device__ __forceinline__ void argmax16(float bv, int kg, int* dst) {
    int bi = kg;
#pragma unroll
    for (int m = 1; m <= 8; m <<= 1) {
        const float ov = __shfl_xor(bv, m);
        const int   oi = __shfl_xor(bi, m);
        if (ov > bv || (ov == bv && oi < bi)) { bv = ov; bi = oi; }
    }
    if (kg == 0) *dst = bi;
}

// ========= Kernel B: per (sample,batch) — MLP, argmax, components, pooling =========
__global__ __launch_bounds__(256) void sample_kernel(
    const float* __restrict__ noise,
    const float* __restrict__ cW1, const float* __restrict__ cb1,
    const float* __restrict__ cW2, const float* __restrict__ cb2,
    const unsigned long long* __restrict__ abits_ws,
    const unsigned long long* __restrict__ mbits_ws,
    float* __restrict__ out, int* __restrict__ gNcl)
{
    const int sb = blockIdx.x;
    const int b  = sb & (B_ - 1);
    const int t  = threadIdx.x;
    __shared__ float xa[N_ * H_];    // x_all, chunk-XOR-swizzled: chunk cc of row i at cc^(i&7)
    __shared__ int   concepts[N_];
    __shared__ unsigned long long reachL[N_];
    __shared__ unsigned long long cmS[N_];
    __shared__ unsigned long long roS[N_];
    __shared__ unsigned long long abS[N_];
    __shared__ unsigned int presLo, presHi;

    const unsigned long long mb = mbits_ws[b];
    if (t < 64) abS[t] = abits_ws[b * N_ + t];
    if (t == 0) { presLo = 0u; presHi = 0u; }

    // stage xa = x_emb[b] + 0.5*noise[sb]
    {
        const float4* e4 = (const float4*)(out + OFF_XEMB + (size_t)b * N_ * H_);
        const float4* n4 = (const float4*)(noise + (size_t)sb * N_ * H_);
        float4* x4 = (float4*)xa;
        for (int idx = t; idx < N_ * 32; idx += 256) {
            const int i = idx >> 5, cc = idx & 31;
            const float4 ev = e4[idx], nv = n4[idx];
            float4 v;
            v.x = ev.x + SIGMA_ * nv.x;  v.y = ev.y + SIGMA_ * nv.y;
            v.z = ev.z + SIGMA_ * nv.z;  v.w = ev.w + SIGMA_ * nv.w;
            x4[i * 32 + (cc ^ (i & 7))] = v;
        }
    }
    __syncthreads();

    // ---- fused: hidden = relu(xa@cW1+cb1); logits = hidden@cW2+cb2; argmax ----
    // thread t: node group ng = t>>4 (nodes 4ng..4ng+3), k chunk kg = t&15 (k in [8kg,8kg+8))
    const int ng = t >> 4, kg = t & 15;
    float acc[4][8] = {};
    {
        const float4* x4 = (const float4*)xa;
        const int swzb = 4 * (ng & 1);
        for (int cc = 0; cc < 32; ++cc) {
            float xv[4][4];
#pragma unroll
            for (int r = 0; r < 4; ++r) {
                const float4 tmp = x4[(4 * ng + r) * 32 + (cc ^ (swzb + r))];
                xv[r][0] = tmp.x; xv[r][1] = tmp.y; xv[r][2] = tmp.z; xv[r][3] = tmp.w;
            }
#pragma unroll
            for (int dd = 0; dd < 4; ++dd) {
                const int d = cc * 4 + dd;
                const float4 wa = *(const float4*)(cW1 + d * H_ + 8 * kg);
                const float4 wb = *(const float4*)(cW1 + d * H_ + 8 * kg + 4);
                const float wf[8] = {wa.x, wa.y, wa.z, wa.w, wb.x, wb.y, wb.z, wb.w};
#pragma unroll
                for (int j = 0; j < 8; ++j)
#pragma unroll
                    for (int r = 0; r < 4; ++r) acc[r][j] += xv[r][dd] * wf[j];
            }
        }
    }
    {
        const float4 ba = *(const float4*)(cb1 + 8 * kg);
        const float4 bb = *(const float4*)(cb1 + 8 * kg + 4);
        const float bf[8] = {ba.x, ba.y, ba.z, ba.w, bb.x, bb.y, bb.z, bb.w};
        const float cb2v = cb2[kg];
        // one node at a time, FULLY UNROLLED (static indexing only — no scratch),
        // pl/h/wf2 dead after each iteration -> compiler reuses registers
#pragma unroll
        for (int r = 0; r < 4; ++r) {
            float h[8];
#pragma unroll
            for (int j = 0; j < 8; ++j) h[j] = fmaxf(acc[r][j] + bf[j], 0.0f);
            float pl[16] = {};
#pragma unroll
            for (int j = 0; j < 8; ++j) {
                const float4* w2r = (const float4*)(cW2 + (8 * kg + j) * C_);
                const float4 w0 = w2r[0], w1 = w2r[1], w2v = w2r[2], w3 = w2r[3];
                const float wf2[16] = {w0.x, w0.y, w0.z, w0.w, w1.x, w1.y, w1.z, w1.w,
                                       w2v.x, w2v.y, w2v.z, w2v.w, w3.x, w3.y, w3.z, w3.w};
#pragma unroll
                for (int c = 0; c < C_; ++c) pl[c] += h[j] * wf2[c];
            }
            const float l = rscat16(pl, kg) + cb2v;   // lane kg: logit[node][concept kg]
            argmax16(l, kg, &concepts[4 * ng + r]);
        }
    }
    __syncthreads();

    // ---- connected components on same-concept masked subgraph via bitset closure ----
    unsigned long long reach = 0ull;
    int masked_i = 0;
    if (t < 64) {
        masked_i = (int)((mb >> t) & 1ull);
        if (masked_i) {
            const int ci = concepts[t];
            unsigned long long mm = abS[t] & mb;
            unsigned long long em = 0ull;
            while (mm) {
                const int j = __builtin_ctzll(mm);
                if (concepts[j] == ci) em |= (1ull << j);
                mm &= mm - 1;
            }
            reach = em | (1ull << t);
        }
        reachL[t] = reach;
    }
    __syncthreads();
    for (;;) {                                    // fixpoint with early exit
        unsigned long long r = reach;
        if (masked_i) {
            unsigned long long mm = reach & ~(1ull << t);
            while (mm) {
                const int j = __builtin_ctzll(mm);
                r |= reachL[j];
                mm &= mm - 1;
            }
        }
        const int changed = (r != reach);
        __syncthreads();
        if (t < 64) reachL[t] = r;
        reach = r;
        if (!__syncthreads_or(changed)) break;
    }
    int root = 0;
    if (masked_i) {
        root = __builtin_ctzll(reach);           // min node index in component
        if (root < 32) atomicOr(&presLo, 1u << root);
        else           atomicOr(&presHi, 1u << (root - 32));
    }
    __syncthreads();
    const unsigned long long present =
        ((unsigned long long)presHi << 32) | (unsigned long long)presLo;
    const int ncl = __popcll(present);
    if (t < 64) {
        int a_i = 0;
        if (masked_i) {
            a_i = __popcll(present & ((1ull << root) - 1ull)) + 1;   // compact 1-based id
            if (root == t) {                     // component representative
                cmS[a_i - 1] = reach;            // member bitmask
                unsigned long long ro = 0ull, mm = reach;
                while (mm) { const int j = __builtin_ctzll(mm); ro |= abS[j]; mm &= mm - 1; }
                roS[a_i - 1] = ro;               // OR of adjacency rows of members
            }
        }
        out[OFF_ASGN + (size_t)sb * N_ + t] = (float)a_i;
    }
    __syncthreads();

    // ---- x_new: gather per (cluster, d) over member bitmask, one global atomic each ----
    for (int e = t; e < ncl * H_; e += 256) {
        const int c = e >> 7, d = e & 127;
        unsigned long long mm = cmS[c];
        float s = 0.0f;
        while (mm) {
            const int j = __builtin_ctzll(mm);
            s += xa[j * H_ + ((((d >> 2) ^ (j & 7)) << 2) | (d & 3))];
            mm &= mm - 1;
        }
        atomicAdd(&out[OFF_XNEW + (size_t)b * N_ * H_ + e], s);
    }
    // ---- adj_new: count (0/1) connections between clusters ----
    {
        int* adjCnt = (int*)out + OFF_ADJN;
        for (int idx = t; idx < ncl * N_; idx += 256) {
            const int c1 = idx >> 6, c2 = idx & 63;
            if (c2 < ncl && (roS[c1] & cmS[c2]))
                atomicAdd(&adjCnt[b * N_ * N_ + idx], 1);
        }
    }
    if (t == 0) atomicMax(&gNcl[b], ncl);
}

// ================= Kernel C: finalize (means, mask_new) =================
__global__ __launch_bounds__(256) void finalize_kernel(
    float* __restrict__ out, const int* __restrict__ gNcl)
{
    const int idx = blockIdx.x * 256 + threadIdx.x;
    if (idx < OFF_ADJN) {
        out[idx] = out[idx] / 100.0f;                     // x_new mean over S=100
    } else if (idx < OFF_ASGN) {
        const int c = ((const int*)out)[idx];             // adj counts accumulated as int
        out[idx] = (float)c / 100.0f;
    } else {
        const int m = idx - OFF_ASGN;
        if (m < B_ * N_) {
            const int bb = m >> 6, k = m & 63;
            out[OFF_MSKN + m] = (k < gNcl[bb]) ? 1.0f : 0.0f;
        }
    }
}

extern "C" void kernel_launch(void* const* d_in, const int* in_sizes, int n_in,
                              void* d_out, int out_size, void* d_ws, size_t ws_size,
                              hipStream_t stream) {
    (void)in_sizes; (void)n_in; (void)out_size; (void)ws_size;
    const float* x    = (const float*)d_in[0];
    const float* adj  = (const float*)d_in[1];
    const void*  mskp = d_in[2];
    const float* W1   = (const float*)d_in[3];
    const float* b1   = (const float*)d_in[4];
    const float* W2   = (const float*)d_in[5];
    const float* b2   = (const float*)d_in[6];
    const float* cW1  = (const float*)d_in[7];
    const float* cb1  = (const float*)d_in[8];
    const float* cW2  = (const float*)d_in[9];
    const float* cb2  = (const float*)d_in[10];
    const float* noise = (const float*)d_in[11];
    float* out = (float*)d_out;

    // ws: [0,256) gNcl (32 ints), [256, 256+16384) adjacency bitmasks, then mask bitmasks
    int* gNcl = (int*)d_ws;
    unsigned long long* abits_ws = (unsigned long long*)((char*)d_ws + 256);
    unsigned long long* mbits_ws = (unsigned long long*)((char*)d_ws + 256 + 16384);

    hipMemsetAsync(d_out, 0, (size_t)OFF_ASGN * sizeof(float), stream); // zero x_new + adj_new accumulators
    hipMemsetAsync(d_ws, 0, 256, stream);                               // zero gNcl

    gcn_kernel<<<B_, 256, 0, stream>>>(x, adj, mskp, W1, b1, W2, b2,
                                       out, abits_ws, mbits_ws);
    sample_kernel<<<S_ * B_, 256, 0, stream>>>(noise, cW1, cb1, cW2, cb2,
                                               abits_ws, mbits_ws, out, gNcl);
    finalize_kernel<<<(OFF_ASGN + B_ * N_ + 255) / 256, 256, 0, stream>>>(out, gNcl);
}

// Round 5
// 526.553 us; speedup vs baseline: 1.2099x; 1.0034x over previous
//
#include <hip/hip_runtime.h>
#include <cstdint>

#define B_ 32
#define N_ 64
#define H_ 128
#define S_ 100
#define C_ 16
#define SIGMA_ 0.5f

// output layout (floats): x_new | adj_new | assignments | x_emb | mask_new
#define OFF_XNEW 0
#define OFF_ADJN 262144
#define OFF_ASGN 393216
#define OFF_XEMB 598016
#define OFF_MSKN 860160

// ws layout (bytes)
#define WS_NCL_OFF   0            // 3200 int
#define WS_ABITS_OFF 16384        // 32*64 u64
#define WS_MBITS_OFF 32768        // 32 u64
#define WS_PART_OFF  40960        // 3200*8192 f32 = 104857600 B
#define WS_ADJB_OFF  104898560    // 3200*64 u64 = 1638400 B
#define WS_NEED      106536960ull

// ---- mask dtype sniffing: mask[0,0] is guaranteed true (counts >= 32) ----
__device__ __forceinline__ int read_mask_elem(const void* mp, int idx) {
    const unsigned int* u = (const unsigned int*)mp;
    const unsigned int w0 = u[0], w1 = u[1];
    if (w0 == 1u) {
        if (w1 == 1u) return ((const int*)mp)[idx] != 0;      // int32 (elem1 also true)
        return ((const int*)mp)[2 * idx] != 0;                 // int64
    }
    if (w0 == 0x3f800000u) return ((const float*)mp)[idx] != 0.0f;   // float32
    if (w0 == 0u) return ((const double*)mp)[idx] != 0.0;            // float64
    return ((const unsigned char*)mp)[idx] != 0;                     // bool bytes
}

// ================= Kernel A: 2-layer GCN, adj/mask bitmasks =================
__global__ __launch_bounds__(256) void gcn_kernel(
    const float* __restrict__ x, const float* __restrict__ adj,
    const void* __restrict__ maskp,
    const float* __restrict__ W1, const float* __restrict__ b1,
    const float* __restrict__ W2, const float* __restrict__ b2,
    float* __restrict__ out,
    unsigned long long* __restrict__ abits_ws,
    unsigned long long* __restrict__ mbits_ws)
{
    const int b = blockIdx.x;
    const int t = threadIdx.x;
    __shared__ float Xs[N_][130];   // padded strides to cut bank conflicts
    __shared__ float Hs[N_][130];
    __shared__ float An[N_][65];
    __shared__ float dsh[N_];
    __shared__ unsigned long long mb_sh;

    if (t < 64) {
        const int mv = read_mask_elem(maskp, b * N_ + t);
        const unsigned long long bal = __ballot(mv != 0);
        if (t == 0) { mb_sh = bal; mbits_ws[b] = bal; }
    }
    // adj -> An (diag forced to 1 for normalization) + adjacency bitmasks (ORIGINAL adj)
    for (int row = (t >> 6); row < N_; row += 4) {
        const int j = t & 63;
        const float v = adj[((size_t)b * N_ + row) * N_ + j];
        const unsigned long long bal = __ballot(v > 0.0f);
        if (j == 0) abits_ws[b * N_ + row] = bal;
        An[row][j] = (row == j) ? 1.0f : v;
    }
    __syncthreads();
    if (t < 64) {
        float s = 0.0f;
        for (int j = 0; j < N_; ++j) s += An[t][j];
        if (s < 1.0f) s = 1.0f;
        dsh[t] = 1.0f / sqrtf(s);
    }
    __syncthreads();
    for (int e = t; e < N_ * N_; e += 256) {
        const int i = e >> 6, j = e & 63;
        An[i][j] *= dsh[i] * dsh[j];
    }
    for (int e = t; e < N_ * H_; e += 256)
        Xs[e >> 7][e & 127] = x[(size_t)b * N_ * H_ + e];
    __syncthreads();

    const int ng = t & 15, kg = t >> 4;          // 4 nodes x 8 contiguous k per thread
    const unsigned long long mb = mb_sh;

    // ---- layer 1: Hs = Xs @ W1 ----
    {
        float acc[4][8] = {};
        for (int d = 0; d < H_; ++d) {
            float xv[4];
#pragma unroll
            for (int r = 0; r < 4; ++r) xv[r] = Xs[4 * ng + r][d];
            const float4 wa = *(const float4*)(W1 + d * H_ + 8 * kg);
            const float4 wb = *(const float4*)(W1 + d * H_ + 8 * kg + 4);
            const float wf[8] = {wa.x, wa.y, wa.z, wa.w, wb.x, wb.y, wb.z, wb.w};
#pragma unroll
            for (int j = 0; j < 8; ++j)
#pragma unroll
                for (int r = 0; r < 4; ++r) acc[r][j] += xv[r] * wf[j];
        }
#pragma unroll
        for (int r = 0; r < 4; ++r)
#pragma unroll
            for (int j = 0; j < 8; ++j) Hs[4 * ng + r][8 * kg + j] = acc[r][j];
    }
    __syncthreads();
    // ---- xe = relu(An @ Hs + b1) * mask -> Xs ----
    {
        float acc[4][8] = {};
        for (int j2 = 0; j2 < N_; ++j2) {
            float av[4];
#pragma unroll
            for (int r = 0; r < 4; ++r) av[r] = An[4 * ng + r][j2];
            float hv[8];
#pragma unroll
            for (int j = 0; j < 8; ++j) hv[j] = Hs[j2][8 * kg + j];
#pragma unroll
            for (int j = 0; j < 8; ++j)
#pragma unroll
                for (int r = 0; r < 4; ++r) acc[r][j] += av[r] * hv[j];
        }
        const float4 ba = *(const float4*)(b1 + 8 * kg);
        const float4 bb = *(const float4*)(b1 + 8 * kg + 4);
        const float bf[8] = {ba.x, ba.y, ba.z, ba.w, bb.x, bb.y, bb.z, bb.w};
#pragma unroll
        for (int r = 0; r < 4; ++r) {
            const int i = 4 * ng + r;
            const float m = ((mb >> i) & 1ull) ? 1.0f : 0.0f;
#pragma unroll
            for (int j = 0; j < 8; ++j)
                Xs[i][8 * kg + j] = fmaxf(acc[r][j] + bf[j], 0.0f) * m;
        }
    }
    __syncthreads();
    // ---- layer 2: Hs = Xs @ W2 ----
    {
        float acc[4][8] = {};
        for (int d = 0; d < H_; ++d) {
            float xv[4];
#pragma unroll
            for (int r = 0; r < 4; ++r) xv[r] = Xs[4 * ng + r][d];
            const float4 wa = *(const float4*)(W2 + d * H_ + 8 * kg);
            const float4 wb = *(const float4*)(W2 + d * H_ + 8 * kg + 4);
            const float wf[8] = {wa.x, wa.y, wa.z, wa.w, wb.x, wb.y, wb.z, wb.w};
#pragma unroll
            for (int j = 0; j < 8; ++j)
#pragma unroll
                for (int r = 0; r < 4; ++r) acc[r][j] += xv[r] * wf[j];
        }
        __syncthreads();
#pragma unroll
        for (int r = 0; r < 4; ++r)
#pragma unroll
            for (int j = 0; j < 8; ++j) Hs[4 * ng + r][8 * kg + j] = acc[r][j];
    }
    __syncthreads();
    // ---- x_emb = relu(An @ Hs + b2) * mask -> global ----
    {
        float acc[4][8] = {};
        for (int j2 = 0; j2 < N_; ++j2) {
            float av[4];
#pragma unroll
            for (int r = 0; r < 4; ++r) av[r] = An[4 * ng + r][j2];
            float hv[8];
#pragma unroll
            for (int j = 0; j < 8; ++j) hv[j] = Hs[j2][8 * kg + j];
#pragma unroll
            for (int j = 0; j < 8; ++j)
#pragma unroll
                for (int r = 0; r < 4; ++r) acc[r][j] += av[r] * hv[j];
        }
        const float4 ba = *(const float4*)(b2 + 8 * kg);
        const float4 bb = *(const float4*)(b2 + 8 * kg + 4);
        const float bf[8] = {ba.x, ba.y, ba.z, ba.w, bb.x, bb.y, bb.z, bb.w};
#pragma unroll
        for (int r = 0; r < 4; ++r) {
            const int i = 4 * ng + r;
            const float m = ((mb >> i) & 1ull) ? 1.0f : 0.0f;
#pragma unroll
            for (int j = 0; j < 8; ++j)
                out[OFF_XEMB + (size_t)b * N_ * H_ + i * H_ + 8 * kg + j] =
                    fmaxf(acc[r][j] + bf[j], 0.0f) * m;
        }
    }
}

// ---- helpers: reduce-scatter 16 values over 16 contiguous lanes ----
__device__ __forceinline__ float rscat16(float* v, int kg) {
#pragma unroll
    for (int i = 0; i < 8; ++i) {
        const float send = (kg & 8) ? v[i] : v[i + 8];
        const float recv = __shfl_xor(send, 8);
        v[i] = ((kg & 8) ? v[i + 8] : v[i]) + recv;
    }
#pragma unroll
    for (int i = 0; i < 4; ++i) {
        const float send = (kg & 4) ? v[i] : v[i + 4];
        const float recv = __shfl_xor(send, 4);
        v[i] = ((kg & 4) ? v[i + 4] : v[i]) + recv;
    }
#pragma unroll
    for (int i = 0; i < 2; ++i) {
        const float send = (kg & 2) ? v[i] : v[i + 2];
        const float recv = __shfl_xor(send, 2);
        v[i] = ((kg & 2) ? v[i + 2] : v[i]) + recv;
    }
    {
        const float send = (kg & 1) ? v[0] : v[1];
        const float recv = __shfl_xor(send, 1);
        v[0] = ((kg & 1) ? v[1] : v[0]) + recv;
    }
    return v[0];   // lane kg holds full sum for index kg
}

// argmax over the 16-lane group (value bv at concept kg); first-max tie-break
__device__ __forceinline__ void argmax16(float bv, int kg, int* dst) {
    int bi = kg;
#pragma unroll
    for (int m = 1; m <= 8; m <<= 1) {
        const float ov = __shfl_xor(bv, m);
        const int   oi = __shfl_xor(bi, m);
        if (ov > bv || (ov == bv && oi < bi)) { bv = ov; bi = oi; }
    }
    if (kg == 0) *dst = bi;
}

// ========= Kernel B: per (sample,batch) — MLP, argmax, components, pooling =========
// USE_WS=1: store per-sample partials to ws (no global atomics).
// USE_WS=0: legacy atomic accumulation into out (fallback if ws too small).
template <int USE_WS>
__global__ __launch_bounds__(256) void sample_kernel(
    const float* __restrict__ noise,
    const float* __restrict__ cW1, const float* __restrict__ cb1,
    const float* __restrict__ cW2, const float* __restrict__ cb2,
    const unsigned long long* __restrict__ abits_ws,
    const unsigned long long* __restrict__ mbits_ws,
    float* __restrict__ out,
    float* __restrict__ partial,                // [3200][64][128]
    unsigned long long* __restrict__ adjbits,   // [3200][64]
    int* __restrict__ nclArr)                   // [3200] (atomicMax gNcl[b] in fallback)
{
    const int sb = blockIdx.x;
    const int b  = sb & (B_ - 1);
    const int t  = threadIdx.x;
    __shared__ float xa[N_ * H_];    // x_all, chunk-XOR-swizzled: chunk cc of row i at cc^(i&7)
    __shared__ int   concepts[N_];
    __shared__ unsigned long long reachL[N_];
    __shared__ unsigned long long cmS[N_];
    __shared__ unsigned long long roS[N_];
    __shared__ unsigned long long abS[N_];
    __shared__ unsigned int presLo, presHi;

    const unsigned long long mb = mbits_ws[b];
    if (t < 64) abS[t] = abits_ws[b * N_ + t];
    if (t == 0) { presLo = 0u; presHi = 0u; }

    // stage xa = x_emb[b] + 0.5*noise[sb]
    {
        const float4* e4 = (const float4*)(out + OFF_XEMB + (size_t)b * N_ * H_);
        const float4* n4 = (const float4*)(noise + (size_t)sb * N_ * H_);
        float4* x4 = (float4*)xa;
        for (int idx = t; idx < N_ * 32; idx += 256) {
            const int i = idx >> 5, cc = idx & 31;
            const float4 ev = e4[idx], nv = n4[idx];
            float4 v;
            v.x = ev.x + SIGMA_ * nv.x;  v.y = ev.y + SIGMA_ * nv.y;
            v.z = ev.z + SIGMA_ * nv.z;  v.w = ev.w + SIGMA_ * nv.w;
            x4[i * 32 + (cc ^ (i & 7))] = v;
        }
    }
    __syncthreads();

    // ---- fused: hidden = relu(xa@cW1+cb1); logits = hidden@cW2+cb2; argmax ----
    // thread t: node group ng = t>>4 (nodes 4ng..4ng+3), k chunk kg = t&15 (k in [8kg,8kg+8))
    const int ng = t >> 4, kg = t & 15;
    float acc[4][8] = {};
    {
        const float4* x4 = (const float4*)xa;
        const int swzb = 4 * (ng & 1);
        for (int cc = 0; cc < 32; ++cc) {
            float xv[4][4];
#pragma unroll
            for (int r = 0; r < 4; ++r) {
                const float4 tmp = x4[(4 * ng + r) * 32 + (cc ^ (swzb + r))];
                xv[r][0] = tmp.x; xv[r][1] = tmp.y; xv[r][2] = tmp.z; xv[r][3] = tmp.w;
            }
#pragma unroll
            for (int dd = 0; dd < 4; ++dd) {
                const int d = cc * 4 + dd;
                const float4 wa = *(const float4*)(cW1 + d * H_ + 8 * kg);
                const float4 wb = *(const float4*)(cW1 + d * H_ + 8 * kg + 4);
                const float wf[8] = {wa.x, wa.y, wa.z, wa.w, wb.x, wb.y, wb.z, wb.w};
#pragma unroll
                for (int j = 0; j < 8; ++j)
#pragma unroll
                    for (int r = 0; r < 4; ++r) acc[r][j] += xv[r][dd] * wf[j];
            }
        }
    }
    {
        const float4 ba = *(const float4*)(cb1 + 8 * kg);
        const float4 bb = *(const float4*)(cb1 + 8 * kg + 4);
        const float bf[8] = {ba.x, ba.y, ba.z, ba.w, bb.x, bb.y, bb.z, bb.w};
        const float cb2v = cb2[kg];
        // one node at a time, FULLY UNROLLED (static indexing only — no scratch)
#pragma unroll
        for (int r = 0; r < 4; ++r) {
            float h[8];
#pragma unroll
            for (int j = 0; j < 8; ++j) h[j] = fmaxf(acc[r][j] + bf[j], 0.0f);
            float pl[16] = {};
#pragma unroll
            for (int j = 0; j < 8; ++j) {
                const float4* w2r = (const float4*)(cW2 + (8 * kg + j) * C_);
                const float4 w0 = w2r[0], w1 = w2r[1], w2v = w2r[2], w3 = w2r[3];
                const float wf2[16] = {w0.x, w0.y, w0.z, w0.w, w1.x, w1.y, w1.z, w1.w,
                                       w2v.x, w2v.y, w2v.z, w2v.w, w3.x, w3.y, w3.z, w3.w};
#pragma unroll
                for (int c = 0; c < C_; ++c) pl[c] += h[j] * wf2[c];
            }
            const float l = rscat16(pl, kg) + cb2v;   // lane kg: logit[node][concept kg]
            argmax16(l, kg, &concepts[4 * ng + r]);
        }
    }
    __syncthreads();

    // ---- connected components on same-concept masked subgraph via bitset closure ----
    unsigned long long reach = 0ull;
    int masked_i = 0;
    if (t < 64) {
        masked_i = (int)((mb >> t) & 1ull);
        if (masked_i) {
            const int ci = concepts[t];
            unsigned long long mm = abS[t] & mb;
            unsigned long long em = 0ull;
            while (mm) {
                const int j = __builtin_ctzll(mm);
                if (concepts[j] == ci) em |= (1ull << j);
                mm &= mm - 1;
            }
            reach = em | (1ull << t);
        }
        reachL[t] = reach;
    }
    __syncthreads();
    for (;;) {                                    // fixpoint with early exit
        unsigned long long r = reach;
        if (masked_i) {
            unsigned long long mm = reach & ~(1ull << t);
            while (mm) {
                const int j = __builtin_ctzll(mm);
                r |= reachL[j];
                mm &= mm - 1;
            }
        }
        const int changed = (r != reach);
        __syncthreads();
        if (t < 64) reachL[t] = r;
        reach = r;
        if (!__syncthreads_or(changed)) break;
    }
    int root = 0;
    if (masked_i) {
        root = __builtin_ctzll(reach);           // min node index in component
        if (root < 32) atomicOr(&presLo, 1u << root);
        else           atomicOr(&presHi, 1u << (root - 32));
    }
    __syncthreads();
    const unsigned long long present =
        ((unsigned long long)presHi << 32) | (unsigned long long)presLo;
    const int ncl = __popcll(present);
    if (t < 64) {
        int a_i = 0;
        if (masked_i) {
            a_i = __popcll(present & ((1ull << root) - 1ull)) + 1;   // compact 1-based id
            if (root == t) {                     // component representative
                cmS[a_i - 1] = reach;            // member bitmask
                unsigned long long ro = 0ull, mm = reach;
                while (mm) { const int j = __builtin_ctzll(mm); ro |= abS[j]; mm &= mm - 1; }
                roS[a_i - 1] = ro;               // OR of adjacency rows of members
            }
        }
        out[OFF_ASGN + (size_t)sb * N_ + t] = (float)a_i;
    }
    __syncthreads();

    if (USE_WS) {
        // ---- x_new partials: float4 gather per (cluster, d4), plain stores ----
        float* pt = partial + (size_t)sb * (N_ * H_);
        for (int e4 = t; e4 < N_ * 32; e4 += 256) {      // e4 = c*32 + d4
            const int c = e4 >> 5, d4 = e4 & 31;
            float4 s = {0.f, 0.f, 0.f, 0.f};
            if (c < ncl) {
                unsigned long long mm = cmS[c];
                while (mm) {
                    const int j = __builtin_ctzll(mm);
                    const float4 v = *(const float4*)&xa[j * H_ + ((d4 ^ (j & 7)) << 2)];
                    s.x += v.x; s.y += v.y; s.z += v.z; s.w += v.w;
                    mm &= mm - 1;
                }
            }
            *(float4*)&pt[e4 * 4] = s;
        }
        // ---- adj row bitmasks (zeros beyond ncl) ----
        if (t < 64) {
            unsigned long long row = 0ull;
            if (t < ncl) {
                const unsigned long long ro = roS[t];
                for (int c2 = 0; c2 < 64; ++c2)
                    if (c2 < ncl && (ro & cmS[c2])) row |= (1ull << c2);
            }
            adjbits[(size_t)sb * 64 + t] = row;
        }
        if (t == 0) nclArr[sb] = ncl;
    } else {
        // ---- legacy: global atomic accumulation ----
        for (int e = t; e < ncl * H_; e += 256) {
            const int c = e >> 7, d = e & 127;
            unsigned long long mm = cmS[c];
            float s = 0.0f;
            while (mm) {
                const int j = __builtin_ctzll(mm);
                s += xa[j * H_ + ((((d >> 2) ^ (j & 7)) << 2) | (d & 3))];
                mm &= mm - 1;
            }
            atomicAdd(&out[OFF_XNEW + (size_t)b * N_ * H_ + e], s);
        }
        int* adjCnt = (int*)out + OFF_ADJN;
        for (int idx = t; idx < ncl * N_; idx += 256) {
            const int c1 = idx >> 6, c2 = idx & 63;
            if (c2 < ncl && (roS[c1] & cmS[c2]))
                atomicAdd(&adjCnt[b * N_ * N_ + idx], 1);
        }
        if (t == 0) atomicMax(&nclArr[b], ncl);
    }
}

// ============ Kernel C (ws path): reduce partials -> means, mask_new ============
__global__ __launch_bounds__(256) void reduce_kernel(
    const float* __restrict__ partial, const unsigned long long* __restrict__ adjbits,
    const int* __restrict__ nclArr, float* __restrict__ out)
{
    const int idx = blockIdx.x * 256 + threadIdx.x;
    if (idx < 65536) {                       // x_new: float4 per thread
        const int b = idx >> 11, rem = idx & 2047;   // rem = c*32 + d4
        float4 s = {0.f, 0.f, 0.f, 0.f};
        const float* p = partial + (size_t)b * (N_ * H_) + rem * 4;
#pragma unroll 4
        for (int s_ = 0; s_ < S_; ++s_) {
            const float4 v = *(const float4*)(p + (size_t)s_ * (B_ * N_ * H_));
            s.x += v.x; s.y += v.y; s.z += v.z; s.w += v.w;
        }
        s.x *= 0.01f; s.y *= 0.01f; s.z *= 0.01f; s.w *= 0.01f;
        *(float4*)&out[OFF_XNEW + (size_t)b * (N_ * H_) + rem * 4] = s;
    } else if (idx < 65536 + 131072) {       // adj_new
        const int j = idx - 65536;
        const int b = j >> 12, c1 = (j >> 6) & 63, c2 = j & 63;
        int cnt = 0;
#pragma unroll 4
        for (int s_ = 0; s_ < S_; ++s_)
            cnt += (int)((adjbits[((size_t)s_ * B_ + b) * 64 + c1] >> c2) & 1ull);
        out[OFF_ADJN + j] = (float)cnt * 0.01f;
    } else if (idx < 65536 + 131072 + 2048) { // mask_new
        const int m = idx - 196608;
        const int b = m >> 6, k = m & 63;
        int mx = 0;
        for (int s_ = 0; s_ < S_; ++s_) {
            const int v = nclArr[s_ * B_ + b];
            mx = v > mx ? v : mx;
        }
        out[OFF_MSKN + m] = (k < mx) ? 1.0f : 0.0f;
    }
}

// ============ Kernel C (fallback path): finalize means from atomics ============
__global__ __launch_bounds__(256) void finalize_kernel(
    float* __restrict__ out, const int* __restrict__ gNcl)
{
    const int idx = blockIdx.x * 256 + threadIdx.x;
    if (idx < OFF_ADJN) {
        out[idx] = out[idx] / 100.0f;                     // x_new mean over S=100
    } else if (idx < OFF_ASGN) {
        const int c = ((const int*)out)[idx];             // adj counts accumulated as int
        out[idx] = (float)c / 100.0f;
    } else {
        const int m = idx - OFF_ASGN;
        if (m < B_ * N_) {
            const int bb = m >> 6, k = m & 63;
            out[OFF_MSKN + m] = (k < gNcl[bb]) ? 1.0f : 0.0f;
        }
    }
}

extern "C" void kernel_launch(void* const* d_in, const int* in_sizes, int n_in,
                              void* d_out, int out_size, void* d_ws, size_t ws_size,
                              hipStream_t stream) {
    (void)in_sizes; (void)n_in; (void)out_size;
    const float* x    = (const float*)d_in[0];
    const float* adj  = (const float*)d_in[1];
    const void*  mskp = d_in[2];
    const float* W1   = (const float*)d_in[3];
    const float* b1   = (const float*)d_in[4];
    const float* W2   = (const float*)d_in[5];
    const float* b2   = (const float*)d_in[6];
    const float* cW1  = (const float*)d_in[7];
    const float* cb1  = (const float*)d_in[8];
    const float* cW2  = (const float*)d_in[9];
    const float* cb2  = (const float*)d_in[10];
    const float* noise = (const float*)d_in[11];
    float* out = (float*)d_out;

    int* nclArr = (int*)d_ws;
    unsigned long long* abits_ws = (unsigned long long*)((char*)d_ws + WS_ABITS_OFF);
    unsigned long long* mbits_ws = (unsigned long long*)((char*)d_ws + WS_MBITS_OFF);
    float* partial = (float*)((char*)d_ws + WS_PART_OFF);
    unsigned long long* adjbits = (unsigned long long*)((char*)d_ws + WS_ADJB_OFF);

    const bool use_ws = (ws_size >= WS_NEED);

    gcn_kernel<<<B_, 256, 0, stream>>>(x, adj, mskp, W1, b1, W2, b2,
                                       out, abits_ws, mbits_ws);
    if (use_ws) {
        sample_kernel<1><<<S_ * B_, 256, 0, stream>>>(noise, cW1, cb1, cW2, cb2,
                                                      abits_ws, mbits_ws, out,
                                                      partial, adjbits, nclArr);
        reduce_kernel<<<(65536 + 131072 + 2048) / 256, 256, 0, stream>>>(
            partial, adjbits, nclArr, out);
    } else {
        hipMemsetAsync(d_out, 0, (size_t)OFF_ASGN * sizeof(float), stream);
        hipMemsetAsync(d_ws, 0, 256, stream);   // gNcl (nclArr[0..31]) zero
        sample_kernel<0><<<S_ * B_, 256, 0, stream>>>(noise, cW1, cb1, cW2, cb2,
                                                      abits_ws, mbits_ws, out,
                                                      partial, adjbits, nclArr);
        finalize_kernel<<<(OFF_ASGN + B_ * N_ + 255) / 256, 256, 0, stream>>>(out, nclArr);
    }
}

// Round 6
// 519.074 us; speedup vs baseline: 1.2273x; 1.0144x over previous
//
#include <hip/hip_runtime.h>
#include <cstdint>

#define B_ 32
#define N_ 64
#define H_ 128
#define S_ 100
#define C_ 16
#define SIGMA_ 0.5f

// output layout (floats): x_new | adj_new | assignments | x_emb | mask_new
#define OFF_XNEW 0
#define OFF_ADJN 262144
#define OFF_ASGN 393216
#define OFF_XEMB 598016
#define OFF_MSKN 860160

// ws layout (bytes)
#define WS_NCL_OFF   0            // 3200 int
#define WS_ABITS_OFF 16384        // 32*64 u64
#define WS_MBITS_OFF 32768        // 32 u64
#define WS_CONC_OFF  65536        // 3200*64 int = 819200
#define WS_CM_OFF    917504       // 3200*64 u64 = 1638400
#define WS_ADJB_OFF  2555904      // 3200*64 u64 = 1638400
#define WS_XE_OFF    4194304      // 32*64*128 f32 = 1048576
#define WS_PART_OFF  5242880      // 3200*8192 bf16 = 52428800
#define WS_NEED      57671680ull

__device__ __forceinline__ unsigned short f2bf(float f) {   // RNE, finite inputs
    unsigned int u = __float_as_uint(f);
    u += 0x7fffu + ((u >> 16) & 1u);
    return (unsigned short)(u >> 16);
}
__device__ __forceinline__ float bf2f(unsigned short h) {
    return __uint_as_float(((unsigned int)h) << 16);
}

// ---- mask dtype sniffing: mask[0,0] is guaranteed true (counts >= 32) ----
__device__ __forceinline__ int read_mask_elem(const void* mp, int idx) {
    const unsigned int* u = (const unsigned int*)mp;
    const unsigned int w0 = u[0], w1 = u[1];
    if (w0 == 1u) {
        if (w1 == 1u) return ((const int*)mp)[idx] != 0;
        return ((const int*)mp)[2 * idx] != 0;                 // int64
    }
    if (w0 == 0x3f800000u) return ((const float*)mp)[idx] != 0.0f;
    if (w0 == 0u) return ((const double*)mp)[idx] != 0.0;
    return ((const unsigned char*)mp)[idx] != 0;
}

// ============ Kernel A: one GCN layer, column-chunked (grid 32 x 8) ============
// Xout[b, :, cc*16 .. cc*16+16) = relu(An @ (Xin[b] @ W[:, chunk]) + bias) * mask
__global__ __launch_bounds__(256) void gcn_stage(
    const float* __restrict__ Xin, const float* __restrict__ adj,
    const void* __restrict__ maskp,
    const float* __restrict__ W, const float* __restrict__ bias,
    float* __restrict__ Xout,
    unsigned long long* __restrict__ abits_ws,
    unsigned long long* __restrict__ mbits_ws, int emit_bits)
{
    const int b = blockIdx.x, cc = blockIdx.y;
    const int t = threadIdx.x;
    const int tj = t & 63, tc = t >> 6;          // node tj, col-quad tc (4 cols)
    __shared__ float Xs[N_][129];
    __shared__ float An[N_][65];
    __shared__ float Hc[N_][20];
    __shared__ float dsh[N_];
    __shared__ unsigned long long mb_sh;

    if (t < 64) {
        const int mv = read_mask_elem(maskp, b * N_ + t);
        const unsigned long long bal = __ballot(mv != 0);
        if (t == 0) { mb_sh = bal; if (emit_bits && cc == 0) mbits_ws[b] = bal; }
    }
    for (int row = (t >> 6); row < N_; row += 4) {
        const int j = t & 63;
        const float v = adj[((size_t)b * N_ + row) * N_ + j];
        const unsigned long long bal = __ballot(v > 0.0f);
        if (emit_bits && cc == 0 && j == 0) abits_ws[b * N_ + row] = bal;
        An[row][j] = (row == j) ? 1.0f : v;
    }
    for (int e = t; e < N_ * H_; e += 256)
        Xs[e >> 7][e & 127] = Xin[(size_t)b * N_ * H_ + e];
    __syncthreads();
    if (t < 64) {
        float s = 0.0f;
        for (int j = 0; j < N_; ++j) s += An[t][j];
        if (s < 1.0f) s = 1.0f;
        dsh[t] = 1.0f / sqrtf(s);
    }
    __syncthreads();
    for (int e = t; e < N_ * N_; e += 256) {
        const int i = e >> 6, j = e & 63;
        An[i][j] *= dsh[i] * dsh[j];
    }
    // stage 1: Hc[tj][4tc..4tc+4) = Xs[tj] @ W[:, chunk cols]
    {
        float a0 = 0, a1 = 0, a2 = 0, a3 = 0;
        const float* wp = W + cc * 16 + tc * 4;
        for (int d = 0; d < H_; ++d) {
            const float xv = Xs[tj][d];
            const float4 w = *(const float4*)(wp + d * H_);
            a0 += xv * w.x; a1 += xv * w.y; a2 += xv * w.z; a3 += xv * w.w;
        }
        float4 o; o.x = a0; o.y = a1; o.z = a2; o.w = a3;
        *(float4*)&Hc[tj][tc * 4] = o;
    }
    __syncthreads();
    // stage 2: out = relu(An @ Hc + bias) * mask
    {
        float c0 = 0, c1 = 0, c2 = 0, c3 = 0;
        for (int j2 = 0; j2 < N_; ++j2) {
            const float av = An[tj][j2];
            const float4 h = *(const float4*)&Hc[j2][tc * 4];
            c0 += av * h.x; c1 += av * h.y; c2 += av * h.z; c3 += av * h.w;
        }
        const float4 bq = *(const float4*)(bias + cc * 16 + tc * 4);
        const float m = ((mb_sh >> tj) & 1ull) ? 1.0f : 0.0f;
        float4 o;
        o.x = fmaxf(c0 + bq.x, 0.0f) * m; o.y = fmaxf(c1 + bq.y, 0.0f) * m;
        o.z = fmaxf(c2 + bq.z, 0.0f) * m; o.w = fmaxf(c3 + bq.w, 0.0f) * m;
        *(float4*)&Xout[(size_t)b * N_ * H_ + tj * H_ + cc * 16 + tc * 4] = o;
    }
}

// ---- helpers: reduce-scatter 16 values over 16 contiguous lanes ----
__device__ __forceinline__ float rscat16(float* v, int kg) {
#pragma unroll
    for (int i = 0; i < 8; ++i) {
        const float send = (kg & 8) ? v[i] : v[i + 8];
        const float recv = __shfl_xor(send, 8);
        v[i] = ((kg & 8) ? v[i + 8] : v[i]) + recv;
    }
#pragma unroll
    for (int i = 0; i < 4; ++i) {
        const float send = (kg & 4) ? v[i] : v[i + 4];
        const float recv = __shfl_xor(send, 4);
        v[i] = ((kg & 4) ? v[i + 4] : v[i]) + recv;
    }
#pragma unroll
    for (int i = 0; i < 2; ++i) {
        const float send = (kg & 2) ? v[i] : v[i + 2];
        const float recv = __shfl_xor(send, 2);
        v[i] = ((kg & 2) ? v[i + 2] : v[i]) + recv;
    }
    {
        const float send = (kg & 1) ? v[0] : v[1];
        const float recv = __shfl_xor(send, 1);
        v[0] = ((kg & 1) ? v[1] : v[0]) + recv;
    }
    return v[0];
}

__device__ __forceinline__ void argmax16(float bv, int kg, int* dst) {
    int bi = kg;
#pragma unroll
    for (int m = 1; m <= 8; m <<= 1) {
        const float ov = __shfl_xor(bv, m);
        const int   oi = __shfl_xor(bi, m);
        if (ov > bv || (ov == bv && oi < bi)) { bv = ov; bi = oi; }
    }
    if (kg == 0) *dst = bi;
}

// ============ Kernel B1: per (sample,batch) MLP + argmax -> concepts ============
__global__ __launch_bounds__(256) void mlp_kernel(
    const float* __restrict__ xemb, const float* __restrict__ noise,
    const float* __restrict__ cW1, const float* __restrict__ cb1,
    const float* __restrict__ cW2, const float* __restrict__ cb2,
    int* __restrict__ conc)
{
    const int sb = blockIdx.x;
    const int b  = sb & (B_ - 1);
    const int t  = threadIdx.x;
    __shared__ float xa[N_ * H_];    // chunk-XOR-swizzled: chunk cc of row i at cc^(i&7)

    {
        const float4* e4 = (const float4*)(xemb + (size_t)b * N_ * H_);
        const float4* n4 = (const float4*)(noise + (size_t)sb * N_ * H_);
        float4* x4 = (float4*)xa;
        for (int idx = t; idx < N_ * 32; idx += 256) {
            const int i = idx >> 5, cc = idx & 31;
            const float4 ev = e4[idx], nv = n4[idx];
            float4 v;
            v.x = ev.x + SIGMA_ * nv.x;  v.y = ev.y + SIGMA_ * nv.y;
            v.z = ev.z + SIGMA_ * nv.z;  v.w = ev.w + SIGMA_ * nv.w;
            x4[i * 32 + (cc ^ (i & 7))] = v;
        }
    }
    __syncthreads();

    const int ng = t >> 4, kg = t & 15;
    float acc[4][8] = {};
    {
        const float4* x4 = (const float4*)xa;
        const int swzb = 4 * (ng & 1);
        for (int cc = 0; cc < 32; ++cc) {
            float xv[4][4];
#pragma unroll
            for (int r = 0; r < 4; ++r) {
                const float4 tmp = x4[(4 * ng + r) * 32 + (cc ^ (swzb + r))];
                xv[r][0] = tmp.x; xv[r][1] = tmp.y; xv[r][2] = tmp.z; xv[r][3] = tmp.w;
            }
#pragma unroll
            for (int dd = 0; dd < 4; ++dd) {
                const int d = cc * 4 + dd;
                const float4 wa = *(const float4*)(cW1 + d * H_ + 8 * kg);
                const float4 wb = *(const float4*)(cW1 + d * H_ + 8 * kg + 4);
                const float wf[8] = {wa.x, wa.y, wa.z, wa.w, wb.x, wb.y, wb.z, wb.w};
#pragma unroll
                for (int j = 0; j < 8; ++j)
#pragma unroll
                    for (int r = 0; r < 4; ++r) acc[r][j] += xv[r][dd] * wf[j];
            }
        }
    }
    {
        const float4 ba = *(const float4*)(cb1 + 8 * kg);
        const float4 bb = *(const float4*)(cb1 + 8 * kg + 4);
        const float bf[8] = {ba.x, ba.y, ba.z, ba.w, bb.x, bb.y, bb.z, bb.w};
        const float cb2v = cb2[kg];
#pragma unroll
        for (int r = 0; r < 4; ++r) {
            float h[8];
#pragma unroll
            for (int j = 0; j < 8; ++j) h[j] = fmaxf(acc[r][j] + bf[j], 0.0f);
            float pl[16] = {};
#pragma unroll
            for (int j = 0; j < 8; ++j) {
                const float4* w2r = (const float4*)(cW2 + (8 * kg + j) * C_);
                const float4 w0 = w2r[0], w1 = w2r[1], w2v = w2r[2], w3 = w2r[3];
                const float wf2[16] = {w0.x, w0.y, w0.z, w0.w, w1.x, w1.y, w1.z, w1.w,
                                       w2v.x, w2v.y, w2v.z, w2v.w, w3.x, w3.y, w3.z, w3.w};
#pragma unroll
                for (int c = 0; c < C_; ++c) pl[c] += h[j] * wf2[c];
            }
            const float l = rscat16(pl, kg) + cb2v;
            argmax16(l, kg, conc + sb * N_ + 4 * ng + r);
        }
    }
}

// ====== Kernel B2: components + labeling, ONE WAVE PER (s,b) (grid 800x256) ======
__global__ __launch_bounds__(256) void cluster_kernel(
    const int* __restrict__ conc,
    const unsigned long long* __restrict__ abits_ws,
    const unsigned long long* __restrict__ mbits_ws,
    unsigned long long* __restrict__ cm_ws,
    unsigned long long* __restrict__ adjbits,
    int* __restrict__ nclArr, float* __restrict__ asgn_out)
{
    const int w = threadIdx.x >> 6, lane = threadIdx.x & 63;
    const int sb = blockIdx.x * 4 + w;
    const int b = sb & (B_ - 1);
    __shared__ int cl[4][N_];
    __shared__ unsigned long long reachL[4][N_];
    __shared__ unsigned long long cmL[4][N_];
    __shared__ unsigned long long roL[4][N_];
    __shared__ unsigned long long abL[4][N_];

    const unsigned long long mb = mbits_ws[b];
    const unsigned long long abv = abits_ws[b * N_ + lane];
    cl[w][lane] = conc[sb * N_ + lane];
    abL[w][lane] = abv;
    cmL[w][lane] = 0ull; roL[w][lane] = 0ull;
    __syncthreads();

    const int masked = (int)((mb >> lane) & 1ull);
    unsigned long long reach = 0ull;
    if (masked) {
        const int ci = cl[w][lane];
        unsigned long long mm = abv & mb, em = 0ull;
        while (mm) {
            const int j = __builtin_ctzll(mm);
            if (cl[w][j] == ci) em |= (1ull << j);
            mm &= mm - 1;
        }
        reach = em | (1ull << lane);
    }
    reachL[w][lane] = reach;
    __syncthreads();
    for (;;) {
        unsigned long long r = reach;
        if (masked) {
            unsigned long long mm = reach & ~(1ull << lane);
            while (mm) {
                const int j = __builtin_ctzll(mm);
                r |= reachL[w][j];
                mm &= mm - 1;
            }
        }
        const int changed = (r != reach);
        __syncthreads();
        reachL[w][lane] = r;
        reach = r;
        if (!__syncthreads_or(changed)) break;
    }
    const int root = masked ? __builtin_ctzll(reach) : 0;
    const unsigned long long present = __ballot(masked && (root == lane));
    const int ncl = __popcll(present);
    const int a_i = masked ? (__popcll(present & ((1ull << root) - 1ull)) + 1) : 0;
    if (masked && root == lane) {
        unsigned long long ro = 0ull, mm = reach;
        while (mm) { const int j = __builtin_ctzll(mm); ro |= abL[w][j]; mm &= mm - 1; }
        cmL[w][a_i - 1] = reach;
        roL[w][a_i - 1] = ro;
    }
    __syncthreads();
    asgn_out[(size_t)sb * N_ + lane] = (float)a_i;
    cm_ws[(size_t)sb * N_ + lane] = cmL[w][lane];
    unsigned long long row = 0ull;
    if (lane < ncl) {
        const unsigned long long ro = roL[w][lane];
        for (int c2 = 0; c2 < ncl; ++c2)
            if (ro & cmL[w][c2]) row |= (1ull << c2);
    }
    adjbits[(size_t)sb * N_ + lane] = row;
    if (lane == 0) nclArr[sb] = ncl;
}

// ====== Kernel B3: per-sample cluster sums (gathered from inputs) -> bf16 partial ======
__global__ __launch_bounds__(256) void pool_kernel(
    const float* __restrict__ xemb, const float* __restrict__ noise,
    const unsigned long long* __restrict__ cm_ws,
    unsigned short* __restrict__ part)
{
    const int sb = blockIdx.x;
    const int b  = sb & (B_ - 1);
    const int t  = threadIdx.x;
    const float4* e4 = (const float4*)(xemb + (size_t)b * N_ * H_);
    const float4* n4 = (const float4*)(noise + (size_t)sb * N_ * H_);
    for (int e = t; e < N_ * 32; e += 256) {          // e = c*32 + d4
        const int c = e >> 5, d4 = e & 31;
        unsigned long long mm = cm_ws[(size_t)sb * N_ + c];
        float4 s = {0.f, 0.f, 0.f, 0.f};
        while (mm) {
            const int j = __builtin_ctzll(mm);
            const float4 ev = e4[j * 32 + d4];
            const float4 nv = n4[j * 32 + d4];
            s.x += ev.x + SIGMA_ * nv.x; s.y += ev.y + SIGMA_ * nv.y;
            s.z += ev.z + SIGMA_ * nv.z; s.w += ev.w + SIGMA_ * nv.w;
            mm &= mm - 1;
        }
        ushort4 o;
        o.x = f2bf(s.x); o.y = f2bf(s.y); o.z = f2bf(s.z); o.w = f2bf(s.w);
        *(ushort4*)&part[(size_t)sb * (N_ * H_) + e * 4] = o;
    }
}

// ============ Kernel C: reduce partials over samples -> means, mask_new ============
__global__ __launch_bounds__(256) void reduce_kernel(
    const unsigned short* __restrict__ part,
    const unsigned long long* __restrict__ adjbits,
    const int* __restrict__ nclArr, float* __restrict__ out)
{
    const int idx = blockIdx.x * 256 + threadIdx.x;
    if (idx < 65536) {                       // x_new: float4 of output per thread
        const int b = idx >> 11, rem = idx & 2047;
        float4 s = {0.f, 0.f, 0.f, 0.f};
        const unsigned short* p = part + (size_t)b * (N_ * H_) + rem * 4;
#pragma unroll 4
        for (int s_ = 0; s_ < S_; ++s_) {
            const ushort4 v = *(const ushort4*)(p + (size_t)s_ * (B_ * N_ * H_));
            s.x += bf2f(v.x); s.y += bf2f(v.y); s.z += bf2f(v.z); s.w += bf2f(v.w);
        }
        s.x *= 0.01f; s.y *= 0.01f; s.z *= 0.01f; s.w *= 0.01f;
        *(float4*)&out[OFF_XNEW + (size_t)b * (N_ * H_) + rem * 4] = s;
    } else if (idx < 65536 + 131072) {       // adj_new
        const int j = idx - 65536;
        const int b = j >> 12, c1 = (j >> 6) & 63, c2 = j & 63;
        int cnt = 0;
#pragma unroll 4
        for (int s_ = 0; s_ < S_; ++s_)
            cnt += (int)((adjbits[((size_t)s_ * B_ + b) * N_ + c1] >> c2) & 1ull);
        out[OFF_ADJN + j] = (float)cnt * 0.01f;
    } else if (idx < 65536 + 131072 + 2048) { // mask_new
        const int m = idx - 196608;
        const int b = m >> 6, k = m & 63;
        int mx = 0;
        for (int s_ = 0; s_ < S_; ++s_) {
            const int v = nclArr[s_ * B_ + b];
            mx = v > mx ? v : mx;
        }
        out[OFF_MSKN + m] = (k < mx) ? 1.0f : 0.0f;
    }
}

extern "C" void kernel_launch(void* const* d_in, const int* in_sizes, int n_in,
                              void* d_out, int out_size, void* d_ws, size_t ws_size,
                              hipStream_t stream) {
    (void)in_sizes; (void)n_in; (void)out_size; (void)ws_size;
    const float* x    = (const float*)d_in[0];
    const float* adj  = (const float*)d_in[1];
    const void*  mskp = d_in[2];
    const float* W1   = (const float*)d_in[3];
    const float* b1   = (const float*)d_in[4];
    const float* W2   = (const float*)d_in[5];
    const float* b2   = (const float*)d_in[6];
    const float* cW1  = (const float*)d_in[7];
    const float* cb1  = (const float*)d_in[8];
    const float* cW2  = (const float*)d_in[9];
    const float* cb2  = (const float*)d_in[10];
    const float* noise = (const float*)d_in[11];
    float* out = (float*)d_out;

    int* nclArr = (int*)d_ws;
    unsigned long long* abits_ws = (unsigned long long*)((char*)d_ws + WS_ABITS_OFF);
    unsigned long long* mbits_ws = (unsigned long long*)((char*)d_ws + WS_MBITS_OFF);
    int* conc = (int*)((char*)d_ws + WS_CONC_OFF);
    unsigned long long* cm_ws = (unsigned long long*)((char*)d_ws + WS_CM_OFF);
    unsigned long long* adjbits = (unsigned long long*)((char*)d_ws + WS_ADJB_OFF);
    float* xe_ws = (float*)((char*)d_ws + WS_XE_OFF);
    unsigned short* part = (unsigned short*)((char*)d_ws + WS_PART_OFF);

    float* xemb = out + OFF_XEMB;

    gcn_stage<<<dim3(B_, 8), 256, 0, stream>>>(x, adj, mskp, W1, b1, xe_ws,
                                               abits_ws, mbits_ws, 1);
    gcn_stage<<<dim3(B_, 8), 256, 0, stream>>>(xe_ws, adj, mskp, W2, b2, xemb,
                                               abits_ws, mbits_ws, 0);
    mlp_kernel<<<S_ * B_, 256, 0, stream>>>(xemb, noise, cW1, cb1, cW2, cb2, conc);
    cluster_kernel<<<S_ * B_ / 4, 256, 0, stream>>>(conc, abits_ws, mbits_ws,
                                                    cm_ws, adjbits, nclArr,
                                                    out + OFF_ASGN);
    pool_kernel<<<S_ * B_, 256, 0, stream>>>(xemb, noise, cm_ws, part);
    reduce_kernel<<<(65536 + 131072 + 2048) / 256, 256, 0, stream>>>(
        part, adjbits, nclArr, out);
}

// Round 7
// 492.048 us; speedup vs baseline: 1.2947x; 1.0549x over previous
//
#include <hip/hip_runtime.h>
#include <cstdint>

#define B_ 32
#define N_ 64
#define H_ 128
#define S_ 100
#define C_ 16
#define SIGMA_ 0.5f

// output layout (floats): x_new | adj_new | assignments | x_emb | mask_new
#define OFF_XNEW 0
#define OFF_ADJN 262144
#define OFF_ASGN 393216
#define OFF_XEMB 598016
#define OFF_MSKN 860160

// ws layout (bytes)
#define WS_NCL_OFF   0            // 3200 int
#define WS_ABITS_OFF 16384        // 32*64 u64
#define WS_MBITS_OFF 32768        // 32 u64
#define WS_CONC_OFF  65536        // 3200*64 int = 819200
#define WS_CM_OFF    917504       // 3200*64 u64 = 1638400
#define WS_ADJB_OFF  2555904      // 3200*64 u64 = 1638400
#define WS_XE_OFF    4194304      // 32*64*128 f32 = 1048576
#define WS_PART_OFF  5242880      // 3200*8192 bf16 = 52428800
#define WS_NEED      57671680ull

__device__ __forceinline__ unsigned short f2bf(float f) {   // RNE, finite inputs
    unsigned int u = __float_as_uint(f);
    u += 0x7fffu + ((u >> 16) & 1u);
    return (unsigned short)(u >> 16);
}
__device__ __forceinline__ float bf2f(unsigned short h) {
    return __uint_as_float(((unsigned int)h) << 16);
}

// ---- mask dtype sniffing: mask[0,0] is guaranteed true (counts >= 32) ----
__device__ __forceinline__ int read_mask_elem(const void* mp, int idx) {
    const unsigned int* u = (const unsigned int*)mp;
    const unsigned int w0 = u[0], w1 = u[1];
    if (w0 == 1u) {
        if (w1 == 1u) return ((const int*)mp)[idx] != 0;
        return ((const int*)mp)[2 * idx] != 0;                 // int64
    }
    if (w0 == 0x3f800000u) return ((const float*)mp)[idx] != 0.0f;
    if (w0 == 0u) return ((const double*)mp)[idx] != 0.0;
    return ((const unsigned char*)mp)[idx] != 0;
}

// ============ Kernel A: one GCN layer, column-chunked (grid 32 x 8) ============
__global__ __launch_bounds__(256) void gcn_stage(
    const float* __restrict__ Xin, const float* __restrict__ adj,
    const void* __restrict__ maskp,
    const float* __restrict__ W, const float* __restrict__ bias,
    float* __restrict__ Xout,
    unsigned long long* __restrict__ abits_ws,
    unsigned long long* __restrict__ mbits_ws, int emit_bits)
{
    const int b = blockIdx.x, cc = blockIdx.y;
    const int t = threadIdx.x;
    const int tj = t & 63, tc = t >> 6;          // node tj, col-quad tc (4 cols)
    __shared__ float Xs[N_][129];
    __shared__ float An[N_][65];
    __shared__ float Hc[N_][20];
    __shared__ float dsh[N_];
    __shared__ unsigned long long mb_sh;

    if (t < 64) {
        const int mv = read_mask_elem(maskp, b * N_ + t);
        const unsigned long long bal = __ballot(mv != 0);
        if (t == 0) { mb_sh = bal; if (emit_bits && cc == 0) mbits_ws[b] = bal; }
    }
    for (int row = (t >> 6); row < N_; row += 4) {
        const int j = t & 63;
        const float v = adj[((size_t)b * N_ + row) * N_ + j];
        const unsigned long long bal = __ballot(v > 0.0f);
        if (emit_bits && cc == 0 && j == 0) abits_ws[b * N_ + row] = bal;
        An[row][j] = (row == j) ? 1.0f : v;
    }
    for (int e = t; e < N_ * H_; e += 256)
        Xs[e >> 7][e & 127] = Xin[(size_t)b * N_ * H_ + e];
    __syncthreads();
    if (t < 64) {
        float s = 0.0f;
        for (int j = 0; j < N_; ++j) s += An[t][j];
        if (s < 1.0f) s = 1.0f;
        dsh[t] = 1.0f / sqrtf(s);
    }
    __syncthreads();
    for (int e = t; e < N_ * N_; e += 256) {
        const int i = e >> 6, j = e & 63;
        An[i][j] *= dsh[i] * dsh[j];
    }
    // stage 1: Hc[tj][4tc..4tc+4) = Xs[tj] @ W[:, chunk cols]
    {
        float a0 = 0, a1 = 0, a2 = 0, a3 = 0;
        const float* wp = W + cc * 16 + tc * 4;
        for (int d = 0; d < H_; ++d) {
            const float xv = Xs[tj][d];
            const float4 w = *(const float4*)(wp + d * H_);
            a0 += xv * w.x; a1 += xv * w.y; a2 += xv * w.z; a3 += xv * w.w;
        }
        float4 o; o.x = a0; o.y = a1; o.z = a2; o.w = a3;
        *(float4*)&Hc[tj][tc * 4] = o;
    }
    __syncthreads();
    // stage 2: out = relu(An @ Hc + bias) * mask
    {
        float c0 = 0, c1 = 0, c2 = 0, c3 = 0;
        for (int j2 = 0; j2 < N_; ++j2) {
            const float av = An[tj][j2];
            const float4 h = *(const float4*)&Hc[j2][tc * 4];
            c0 += av * h.x; c1 += av * h.y; c2 += av * h.z; c3 += av * h.w;
        }
        const float4 bq = *(const float4*)(bias + cc * 16 + tc * 4);
        const float m = ((mb_sh >> tj) & 1ull) ? 1.0f : 0.0f;
        float4 o;
        o.x = fmaxf(c0 + bq.x, 0.0f) * m; o.y = fmaxf(c1 + bq.y, 0.0f) * m;
        o.z = fmaxf(c2 + bq.z, 0.0f) * m; o.w = fmaxf(c3 + bq.w, 0.0f) * m;
        *(float4*)&Xout[(size_t)b * N_ * H_ + tj * H_ + cc * 16 + tc * 4] = o;
    }
}

// ---- helpers: reduce-scatter 16 values over 16 contiguous lanes ----
__device__ __forceinline__ float rscat16(float* v, int kg) {
#pragma unroll
    for (int i = 0; i < 8; ++i) {
        const float send = (kg & 8) ? v[i] : v[i + 8];
        const float recv = __shfl_xor(send, 8);
        v[i] = ((kg & 8) ? v[i + 8] : v[i]) + recv;
    }
#pragma unroll
    for (int i = 0; i < 4; ++i) {
        const float send = (kg & 4) ? v[i] : v[i + 4];
        const float recv = __shfl_xor(send, 4);
        v[i] = ((kg & 4) ? v[i + 4] : v[i]) + recv;
    }
#pragma unroll
    for (int i = 0; i < 2; ++i) {
        const float send = (kg & 2) ? v[i] : v[i + 2];
        const float recv = __shfl_xor(send, 2);
        v[i] = ((kg & 2) ? v[i + 2] : v[i]) + recv;
    }
    {
        const float send = (kg & 1) ? v[0] : v[1];
        const float recv = __shfl_xor(send, 1);
        v[0] = ((kg & 1) ? v[1] : v[0]) + recv;
    }
    return v[0];
}

__device__ __forceinline__ void argmax16(float bv, int kg, int* dst) {
    int bi = kg;
#pragma unroll
    for (int m = 1; m <= 8; m <<= 1) {
        const float ov = __shfl_xor(bv, m);
        const int   oi = __shfl_xor(bi, m);
        if (ov > bv || (ov == bv && oi < bi)) { bv = ov; bi = oi; }
    }
    if (kg == 0) *dst = bi;
}

// ============ Kernel B1: per (sample,batch) MLP + argmax -> concepts ============
// cW1 staged per 16-row K-tile into LDS (8 KB), read from LDS in the FMA loop.
__global__ __launch_bounds__(256) void mlp_kernel(
    const float* __restrict__ xemb, const float* __restrict__ noise,
    const float* __restrict__ cW1, const float* __restrict__ cb1,
    const float* __restrict__ cW2, const float* __restrict__ cb2,
    int* __restrict__ conc)
{
    const int sb = blockIdx.x;
    const int b  = sb & (B_ - 1);
    const int t  = threadIdx.x;
    __shared__ float xa[N_ * H_];    // chunk-XOR-swizzled: chunk cc of row i at cc^(i&7)
    __shared__ float wb[16 * H_];    // current cW1 K-tile [dl][128]

    {
        const float4* e4 = (const float4*)(xemb + (size_t)b * N_ * H_);
        const float4* n4 = (const float4*)(noise + (size_t)sb * N_ * H_);
        float4* x4 = (float4*)xa;
        for (int idx = t; idx < N_ * 32; idx += 256) {
            const int i = idx >> 5, cc = idx & 31;
            const float4 ev = e4[idx], nv = n4[idx];
            float4 v;
            v.x = ev.x + SIGMA_ * nv.x;  v.y = ev.y + SIGMA_ * nv.y;
            v.z = ev.z + SIGMA_ * nv.z;  v.w = ev.w + SIGMA_ * nv.w;
            x4[i * 32 + (cc ^ (i & 7))] = v;
        }
    }
    __syncthreads();

    const int ng = t >> 4, kg = t & 15;
    float acc[4][8] = {};
    {
        const float4* x4 = (const float4*)xa;
        const int swzb = 4 * (ng & 1);
#pragma unroll 1
        for (int kt = 0; kt < 8; ++kt) {               // K-tiles of 16 d
            if (kt) __syncthreads();                   // wb readers of tile kt-1 done
            {
                const float4* wsrc = (const float4*)(cW1 + kt * 16 * H_);
                float4* wd = (float4*)wb;
                wd[t] = wsrc[t];
                wd[t + 256] = wsrc[t + 256];
            }
            __syncthreads();                           // wb tile ready
#pragma unroll
            for (int cc4 = 0; cc4 < 4; ++cc4) {        // 4 xa-chunks (4 d each)
                const int cc = kt * 4 + cc4;
                float xv[4][4];
#pragma unroll
                for (int r = 0; r < 4; ++r) {
                    const float4 tmp = x4[(4 * ng + r) * 32 + (cc ^ (swzb + r))];
                    xv[r][0] = tmp.x; xv[r][1] = tmp.y; xv[r][2] = tmp.z; xv[r][3] = tmp.w;
                }
#pragma unroll
                for (int dd = 0; dd < 4; ++dd) {
                    const int dl = cc4 * 4 + dd;
                    const float4 wa = *(const float4*)(wb + dl * H_ + 8 * kg);
                    const float4 wc = *(const float4*)(wb + dl * H_ + 8 * kg + 4);
                    const float wf[8] = {wa.x, wa.y, wa.z, wa.w, wc.x, wc.y, wc.z, wc.w};
#pragma unroll
                    for (int j = 0; j < 8; ++j)
#pragma unroll
                        for (int r = 0; r < 4; ++r) acc[r][j] += xv[r][dd] * wf[j];
                }
            }
        }
    }
    {
        const float4 ba = *(const float4*)(cb1 + 8 * kg);
        const float4 bb = *(const float4*)(cb1 + 8 * kg + 4);
        const float bf[8] = {ba.x, ba.y, ba.z, ba.w, bb.x, bb.y, bb.z, bb.w};
        const float cb2v = cb2[kg];
#pragma unroll
        for (int r = 0; r < 4; ++r) {
            float h[8];
#pragma unroll
            for (int j = 0; j < 8; ++j) h[j] = fmaxf(acc[r][j] + bf[j], 0.0f);
            float pl[16] = {};
#pragma unroll
            for (int j = 0; j < 8; ++j) {
                const float4* w2r = (const float4*)(cW2 + (8 * kg + j) * C_);
                const float4 w0 = w2r[0], w1 = w2r[1], w2v = w2r[2], w3 = w2r[3];
                const float wf2[16] = {w0.x, w0.y, w0.z, w0.w, w1.x, w1.y, w1.z, w1.w,
                                       w2v.x, w2v.y, w2v.z, w2v.w, w3.x, w3.y, w3.z, w3.w};
#pragma unroll
                for (int c = 0; c < C_; ++c) pl[c] += h[j] * wf2[c];
            }
            const float l = rscat16(pl, kg) + cb2v;
            argmax16(l, kg, conc + sb * N_ + 4 * ng + r);
        }
    }
}

// ====== Kernel B2: components + labeling, ONE WAVE PER (s,b) (grid 800x256) ======
__global__ __launch_bounds__(256) void cluster_kernel(
    const int* __restrict__ conc,
    const unsigned long long* __restrict__ abits_ws,
    const unsigned long long* __restrict__ mbits_ws,
    unsigned long long* __restrict__ cm_ws,
    unsigned long long* __restrict__ adjbits,
    int* __restrict__ nclArr, float* __restrict__ asgn_out)
{
    const int w = threadIdx.x >> 6, lane = threadIdx.x & 63;
    const int sb = blockIdx.x * 4 + w;
    const int b = sb & (B_ - 1);
    __shared__ int cl[4][N_];
    __shared__ unsigned long long reachL[4][N_];
    __shared__ unsigned long long cmL[4][N_];
    __shared__ unsigned long long roL[4][N_];
    __shared__ unsigned long long abL[4][N_];

    const unsigned long long mb = mbits_ws[b];
    const unsigned long long abv = abits_ws[b * N_ + lane];
    cl[w][lane] = conc[sb * N_ + lane];
    abL[w][lane] = abv;
    cmL[w][lane] = 0ull; roL[w][lane] = 0ull;
    __syncthreads();

    const int masked = (int)((mb >> lane) & 1ull);
    unsigned long long reach = 0ull;
    if (masked) {
        const int ci = cl[w][lane];
        unsigned long long mm = abv & mb, em = 0ull;
        while (mm) {
            const int j = __builtin_ctzll(mm);
            if (cl[w][j] == ci) em |= (1ull << j);
            mm &= mm - 1;
        }
        reach = em | (1ull << lane);
    }
    reachL[w][lane] = reach;
    __syncthreads();
    for (;;) {
        unsigned long long r = reach;
        if (masked) {
            unsigned long long mm = reach & ~(1ull << lane);
            while (mm) {
                const int j = __builtin_ctzll(mm);
                r |= reachL[w][j];
                mm &= mm - 1;
            }
        }
        const int changed = (r != reach);
        __syncthreads();
        reachL[w][lane] = r;
        reach = r;
        if (!__syncthreads_or(changed)) break;
    }
    const int root = masked ? __builtin_ctzll(reach) : 0;
    const unsigned long long present = __ballot(masked && (root == lane));
    const int ncl = __popcll(present);
    const int a_i = masked ? (__popcll(present & ((1ull << root) - 1ull)) + 1) : 0;
    if (masked && root == lane) {
        unsigned long long ro = 0ull, mm = reach;
        while (mm) { const int j = __builtin_ctzll(mm); ro |= abL[w][j]; mm &= mm - 1; }
        cmL[w][a_i - 1] = reach;
        roL[w][a_i - 1] = ro;
    }
    __syncthreads();
    asgn_out[(size_t)sb * N_ + lane] = (float)a_i;
    cm_ws[(size_t)sb * N_ + lane] = cmL[w][lane];
    unsigned long long row = 0ull;
    if (lane < ncl) {
        const unsigned long long ro = roL[w][lane];
        for (int c2 = 0; c2 < ncl; ++c2)
            if (ro & cmL[w][c2]) row |= (1ull << c2);
    }
    adjbits[(size_t)sb * N_ + lane] = row;
    if (lane == 0) nclArr[sb] = ncl;
}

// ====== Kernel B3: per-sample cluster sums (gathered from inputs) -> bf16 partial ======
__global__ __launch_bounds__(256) void pool_kernel(
    const float* __restrict__ xemb, const float* __restrict__ noise,
    const unsigned long long* __restrict__ cm_ws,
    unsigned short* __restrict__ part)
{
    const int sb = blockIdx.x;
    const int b  = sb & (B_ - 1);
    const int t  = threadIdx.x;
    const float4* e4 = (const float4*)(xemb + (size_t)b * N_ * H_);
    const float4* n4 = (const float4*)(noise + (size_t)sb * N_ * H_);
    for (int e = t; e < N_ * 32; e += 256) {          // e = c*32 + d4
        const int c = e >> 5, d4 = e & 31;
        unsigned long long mm = cm_ws[(size_t)sb * N_ + c];
        float4 s = {0.f, 0.f, 0.f, 0.f};
        while (mm) {
            const int j = __builtin_ctzll(mm);
            const float4 ev = e4[j * 32 + d4];
            const float4 nv = n4[j * 32 + d4];
            s.x += ev.x + SIGMA_ * nv.x; s.y += ev.y + SIGMA_ * nv.y;
            s.z += ev.z + SIGMA_ * nv.z; s.w += ev.w + SIGMA_ * nv.w;
            mm &= mm - 1;
        }
        ushort4 o;
        o.x = f2bf(s.x); o.y = f2bf(s.y); o.z = f2bf(s.z); o.w = f2bf(s.w);
        *(ushort4*)&part[(size_t)sb * (N_ * H_) + e * 4] = o;
    }
}

// ============ Kernel C: reduce partials over samples -> means, mask_new ============
__global__ __launch_bounds__(256) void reduce_kernel(
    const unsigned short* __restrict__ part,
    const unsigned long long* __restrict__ adjbits,
    const int* __restrict__ nclArr, float* __restrict__ out)
{
    const int idx = blockIdx.x * 256 + threadIdx.x;
    if (idx < 65536) {                       // x_new: float4 of output per thread
        const int b = idx >> 11, rem = idx & 2047;
        float4 s = {0.f, 0.f, 0.f, 0.f};
        const unsigned short* p = part + (size_t)b * (N_ * H_) + rem * 4;
#pragma unroll 4
        for (int s_ = 0; s_ < S_; ++s_) {
            const ushort4 v = *(const ushort4*)(p + (size_t)s_ * (B_ * N_ * H_));
            s.x += bf2f(v.x); s.y += bf2f(v.y); s.z += bf2f(v.z); s.w += bf2f(v.w);
        }
        s.x *= 0.01f; s.y *= 0.01f; s.z *= 0.01f; s.w *= 0.01f;
        *(float4*)&out[OFF_XNEW + (size_t)b * (N_ * H_) + rem * 4] = s;
    } else if (idx < 65536 + 131072) {       // adj_new
        const int j = idx - 65536;
        const int b = j >> 12, c1 = (j >> 6) & 63, c2 = j & 63;
        int cnt = 0;
#pragma unroll 4
        for (int s_ = 0; s_ < S_; ++s_)
            cnt += (int)((adjbits[((size_t)s_ * B_ + b) * N_ + c1] >> c2) & 1ull);
        out[OFF_ADJN + j] = (float)cnt * 0.01f;
    } else if (idx < 65536 + 131072 + 2048) { // mask_new
        const int m = idx - 196608;
        const int b = m >> 6, k = m & 63;
        int mx = 0;
        for (int s_ = 0; s_ < S_; ++s_) {
            const int v = nclArr[s_ * B_ + b];
            mx = v > mx ? v : mx;
        }
        out[OFF_MSKN + m] = (k < mx) ? 1.0f : 0.0f;
    }
}

extern "C" void kernel_launch(void* const* d_in, const int* in_sizes, int n_in,
                              void* d_out, int out_size, void* d_ws, size_t ws_size,
                              hipStream_t stream) {
    (void)in_sizes; (void)n_in; (void)out_size; (void)ws_size;
    const float* x    = (const float*)d_in[0];
    const float* adj  = (const float*)d_in[1];
    const void*  mskp = d_in[2];
    const float* W1   = (const float*)d_in[3];
    const float* b1   = (const float*)d_in[4];
    const float* W2   = (const float*)d_in[5];
    const float* b2   = (const float*)d_in[6];
    const float* cW1  = (const float*)d_in[7];
    const float* cb1  = (const float*)d_in[8];
    const float* cW2  = (const float*)d_in[9];
    const float* cb2  = (const float*)d_in[10];
    const float* noise = (const float*)d_in[11];
    float* out = (float*)d_out;

    int* nclArr = (int*)d_ws;
    unsigned long long* abits_ws = (unsigned long long*)((char*)d_ws + WS_ABITS_OFF);
    unsigned long long* mbits_ws = (unsigned long long*)((char*)d_ws + WS_MBITS_OFF);
    int* conc = (int*)((char*)d_ws + WS_CONC_OFF);
    unsigned long long* cm_ws = (unsigned long long*)((char*)d_ws + WS_CM_OFF);
    unsigned long long* adjbits = (unsigned long long*)((char*)d_ws + WS_ADJB_OFF);
    float* xe_ws = (float*)((char*)d_ws + WS_XE_OFF);
    unsigned short* part = (unsigned short*)((char*)d_ws + WS_PART_OFF);

    float* xemb = out + OFF_XEMB;

    gcn_stage<<<dim3(B_, 8), 256, 0, stream>>>(x, adj, mskp, W1, b1, xe_ws,
                                               abits_ws, mbits_ws, 1);
    gcn_stage<<<dim3(B_, 8), 256, 0, stream>>>(xe_ws, adj, mskp, W2, b2, xemb,
                                               abits_ws, mbits_ws, 0);
    mlp_kernel<<<S_ * B_, 256, 0, stream>>>(xemb, noise, cW1, cb1, cW2, cb2, conc);
    cluster_kernel<<<S_ * B_ / 4, 256, 0, stream>>>(conc, abits_ws, mbits_ws,
                                                    cm_ws, adjbits, nclArr,
                                                    out + OFF_ASGN);
    pool_kernel<<<S_ * B_, 256, 0, stream>>>(xemb, noise, cm_ws, part);
    reduce_kernel<<<(65536 + 131072 + 2048) / 256, 256, 0, stream>>>(
        part, adjbits, nclArr, out);
}